// Round 2
// baseline (1017.884 us; speedup 1.0000x reference)
//
#include <hip/hip_runtime.h>
#include <hip/hip_bf16.h>
#include <math.h>

// PsiQRH block, MI355X. B=8 S=4096 QD=4 DM=1024 H=16 HD=64.
// Round 2: split-precision (bf16 hi+lo) GEMM to fix absmax 2.78e-2 -> ~1e-3.
// Batch processed in 2 halves of 4 to fit 132MiB workspace.

#define DEV static __device__ __forceinline__
typedef unsigned int uint32;

typedef __attribute__((ext_vector_type(8))) short bf16x8;
typedef __attribute__((ext_vector_type(4))) float f32x4;

DEV float2 cmulf(float2 a, float2 b) {
  return make_float2(a.x * b.x - a.y * b.y, a.x * b.y + a.y * b.x);
}
DEV unsigned short f2bf(float f) {
  __hip_bfloat16 h = __float2bfloat16(f);
  return *reinterpret_cast<unsigned short*>(&h);
}
DEV uint32 packhl(float f) {
  unsigned short h = f2bf(f);
  uint32 hb = ((uint32)h) << 16;
  float fh = __uint_as_float(hb);
  unsigned short lo = f2bf(f - fh);
  return (uint32)h | (((uint32)lo) << 16);
}
DEV bf16x8 mkfrag(uint32 a, uint32 b, uint32 c, uint32 d) {
  union { uint4 u; bf16x8 v; } x;
  x.u = make_uint4(a, b, c, d);
  return x.v;
}

// ---------------- fractal pass 1: 1024-pt FFTs over a (z[n]=xp[2n]+i*xp[2n+1], n=2048a+b) ----
__global__ __launch_bounds__(512) void kx_fr_pass1(const float* __restrict__ x,
    const float* __restrict__ W_in, const float* __restrict__ b_in,
    float2* __restrict__ zmid) {
  __shared__ float2 fb[8 * 1024];
  const int t = threadIdx.x, l = t & 63, w = t >> 6;
  const int btile = blockIdx.x, bz = blockIdx.y;
  const int bcol = btile * 8 + w;
  const int d = 2 * (bcol & 511);
  const int soff = bcol >> 9;
  const float w00 = W_in[d],     w10 = W_in[1024 + d], w20 = W_in[2048 + d], w30 = W_in[3072 + d];
  const float w01 = W_in[d + 1], w11 = W_in[1025 + d], w21 = W_in[2049 + d], w31 = W_in[3073 + d];
  const float bi0 = b_in[d], bi1 = b_in[d + 1];
  const float* xb = x + (size_t)bz * 4096 * 4;
  #pragma unroll
  for (int i = 0; i < 16; ++i) {
    int a = i * 64 + l;
    int s = 4 * a + soff;
    float4 xv = *(const float4*)(xb + (size_t)s * 4);
    float z0 = fmaf(xv.x, w00, fmaf(xv.y, w10, fmaf(xv.z, w20, fmaf(xv.w, w30, bi0))));
    float z1 = fmaf(xv.x, w01, fmaf(xv.y, w11, fmaf(xv.z, w21, fmaf(xv.w, w31, bi1))));
    fb[w * 1024 + a] = make_float2(z0, z1);
  }
  __syncthreads();
  for (int st = 0; st < 10; ++st) {
    int hl = 9 - st;
    int half = 1 << hl;
    float invL = 1.0f / (float)(half << 1);
    #pragma unroll
    for (int u = 0; u < 8; ++u) {
      int bf = u * 64 + l;
      int blk = bf >> hl, tt = bf & (half - 1);
      int i1 = w * 1024 + (blk << (hl + 1)) + tt;
      float2 a0 = fb[i1], b0 = fb[i1 + half];
      float sn, cs;
      __sincosf(-6.28318530717958647692f * (float)tt * invL, &sn, &cs);
      fb[i1] = make_float2(a0.x + b0.x, a0.y + b0.y);
      fb[i1 + half] = cmulf(make_float2(a0.x - b0.x, a0.y - b0.y), make_float2(cs, sn));
    }
    __syncthreads();
  }
  float2* dst = zmid + (size_t)bz * (1024 * 2048);
  #pragma unroll
  for (int i = 0; i < 16; ++i) {
    int idx = i * 512 + t;
    int w8 = idx & 7, cnat = idx >> 3;
    float2 v = fb[w8 * 1024 + (int)(__brev((unsigned)cnat) >> 22)];
    dst[(size_t)cnat * 2048 + btile * 8 + w8] = v;
  }
}

DEV float block_reduce256(float* red, int t, float v) {
  red[t] = v; __syncthreads();
  for (int s = 128; s; s >>= 1) { if (t < s) red[t] += red[t + s]; __syncthreads(); }
  float r = red[0]; __syncthreads();
  return r;
}

// ---------------- fractal pass 2: twiddle + 2048-pt FFT over b, untwist, log-log moments -----
__global__ __launch_bounds__(256) void kx_fr_pass2(const float2* __restrict__ zmid,
    float* __restrict__ partials, float* __restrict__ sparts) {
  __shared__ float2 fb[2 * 2048];
  __shared__ float red[256];
  const int t = threadIdx.x, l = t & 63, w = t >> 6;
  const int cg = blockIdx.x, bz = blockIdx.y;
  const int col = w >> 1;
  const int l128 = (w & 1) * 64 + l;
  const int c = (cg == 0) ? (col ? 512 : 0) : (col ? (1024 - cg) : cg);
  const float2* src = zmid + ((size_t)bz * 1024 + c) * 2048;
  #pragma unroll
  for (int i = 0; i < 16; ++i) {
    int bb = i * 128 + l128;
    float2 z = src[bb];
    float fr = (float)(bb * c) * (1.0f / 2097152.0f);
    float sn, cs;
    __sincosf(-6.28318530717958647692f * fr, &sn, &cs);
    fb[col * 2048 + bb] = cmulf(z, make_float2(cs, sn));
  }
  __syncthreads();
  for (int st = 0; st < 11; ++st) {
    int hl = 10 - st;
    int half = 1 << hl;
    float invL = 1.0f / (float)(half << 1);
    #pragma unroll
    for (int u = 0; u < 8; ++u) {
      int bf = u * 128 + l128;
      int blk = bf >> hl, tt = bf & (half - 1);
      int i1 = col * 2048 + (blk << (hl + 1)) + tt;
      float2 a0 = fb[i1], b0 = fb[i1 + half];
      float sn, cs;
      __sincosf(-6.28318530717958647692f * (float)tt * invL, &sn, &cs);
      fb[i1] = make_float2(a0.x + b0.x, a0.y + b0.y);
      fb[i1 + half] = cmulf(make_float2(a0.x - b0.x, a0.y - b0.y), make_float2(cs, sn));
    }
    __syncthreads();
  }
  const int mcol = (cg == 0) ? col : (1 - col);
  float t0 = 0.f, t1 = 0.f, s0 = 0.f, s1 = 0.f, s2 = 0.f;
  #pragma unroll
  for (int i = 0; i < 16; ++i) {
    int dd = i * 128 + l128;
    int md = (c == 0) ? ((2048 - dd) & 2047) : (2047 - dd);
    float2 Zk = fb[col * 2048 + (int)(__brev((unsigned)dd) >> 21)];
    float2 Zm = fb[mcol * 2048 + (int)(__brev((unsigned)md) >> 21)];
    float2 E = make_float2(0.5f * (Zk.x + Zm.x), 0.5f * (Zk.y - Zm.y));
    float2 A = make_float2(Zk.x - Zm.x, Zk.y + Zm.y);
    float2 O = make_float2(0.5f * A.y, -0.5f * A.x);
    int k = c + (dd << 10);
    float fr = (float)k * (1.0f / 4194304.0f);
    float sn, cs;
    __sincosf(-6.28318530717958647692f * fr, &sn, &cs);
    float2 U = cmulf(make_float2(cs, sn), O);
    float Xr = E.x + U.x, Xi = E.y + U.y;
    float P = Xr * Xr + Xi * Xi;
    if (fr > 0.01f && fr < 0.5f) {
      float lp = logf(P + 1e-10f);
      float lk = logf(fr + 1e-10f);
      t0 += lp; t1 += lk * lp;
      s0 += 1.0f; s1 += lk; s2 += lk * lk;
    }
  }
  float T0 = block_reduce256(red, t, t0);
  float T1 = block_reduce256(red, t, t1);
  if (t == 0) {
    partials[((size_t)bz * 512 + cg) * 2 + 0] = T0;
    partials[((size_t)bz * 512 + cg) * 2 + 1] = T1;
  }
  if (bz == 0) {
    float S0 = block_reduce256(red, t, s0);
    float S1 = block_reduce256(red, t, s1);
    float S2 = block_reduce256(red, t, s2);
    if (t == 0) { sparts[cg * 3] = S0; sparts[cg * 3 + 1] = S1; sparts[cg * 3 + 2] = S2; }
  }
}

DEV float block_reduce512(float* sh, int t, float v) {
  sh[t] = v; __syncthreads();
  for (int s = 256; s; s >>= 1) { if (t < s) sh[t] += sh[t + s]; __syncthreads(); }
  float r = sh[0]; __syncthreads();
  return r;
}

// ---------------- finalize: alpha[b]; gelu_k table ---------------------------------------------
__global__ __launch_bounds__(512) void kx_finalize(const float* __restrict__ partials,
    const float* __restrict__ sparts, float* __restrict__ alpha, float* __restrict__ gelu) {
  __shared__ float sh[512];
  __shared__ float lk[4096];
  const int t = threadIdx.x;
  float S0 = block_reduce512(sh, t, sparts[t * 3 + 0]);
  float S1 = block_reduce512(sh, t, sparts[t * 3 + 1]);
  float S2 = block_reduce512(sh, t, sparts[t * 3 + 2]);
  float mk = S1 / S0;
  float var = S2 - mk * S1;
  for (int b = 0; b < 8; ++b) {
    float T0 = block_reduce512(sh, t, partials[((size_t)b * 512 + t) * 2 + 0]);
    float T1 = block_reduce512(sh, t, partials[((size_t)b * 512 + t) * 2 + 1]);
    if (t == 0) {
      float cov = T1 - mk * T0;
      float beta = -cov / (var + 1e-10f);
      float D = fminf(fmaxf((3.0f - beta) * 0.5f, 0.5f), 1.5f);
      alpha[b] = fminf(fmaxf(1.0f + 0.8f * (D - 1.0f), 0.1f), 3.0f);
    }
  }
  for (int s = t; s < 4096; s += 512) {
    int m = (s < 2048) ? s : (4096 - s);
    lk[s] = logf((float)m * (1.0f / 4096.0f) + 1e-8f);
  }
  __syncthreads();
  float ls = 0.f;
  for (int s = t; s < 4096; s += 512) ls += lk[s];
  float mean = block_reduce512(sh, t, ls) * (1.0f / 4096.0f);
  float vs = 0.f;
  for (int s = t; s < 4096; s += 512) { float dv = lk[s] - mean; vs += dv * dv; }
  float sd = sqrtf(block_reduce512(sh, t, vs) * (1.0f / 4095.0f));
  for (int k = t; k < 2049; k += 512) {
    float xn = (lk[k] - mean) / (sd + 1e-8f);
    gelu[k] = 0.5f * xn * (1.0f + erff(xn * 0.70710678118654752440f));
  }
}

// ---------------- W_attn_out transpose -> packed hi/lo bf16 [n][d] ----------------------------
__global__ __launch_bounds__(256) void kx_wt(const float* __restrict__ W, uint32* __restrict__ Wt) {
  __shared__ float tile[64][65];
  const int t = threadIdx.x;
  const int nt = blockIdx.x, dt = blockIdx.y;
  #pragma unroll
  for (int i = 0; i < 16; ++i) {
    int idx = i * 256 + t;
    int r = idx >> 6, cc = idx & 63;
    tile[r][cc] = W[(size_t)(dt * 64 + r) * 1024 + nt * 64 + cc];
  }
  __syncthreads();
  #pragma unroll
  for (int i = 0; i < 16; ++i) {
    int idx = i * 256 + t;
    int r = idx >> 6, cc = idx & 63;
    Wt[(size_t)(nt * 64 + r) * 1024 + dt * 64 + cc] = packhl(tile[cc][r]);
  }
}

// ---------------- spectral filter: irfft(rfft(xp)*cos(phase)) per (b,d), writes packed [bh][d][s]
__global__ __launch_bounds__(256) void kx_filter(const float* __restrict__ x,
    const float* __restrict__ W_in, const float* __restrict__ b_in,
    const float* __restrict__ alpha, const float* __restrict__ gelu,
    const float* __restrict__ alpha_base, const float* __restrict__ phase_shift,
    uint32* __restrict__ xfp, int bz0) {
  __shared__ float2 fb[4 * 2048];
  const int t = threadIdx.x, l = t & 63, w = t >> 6;
  const int g = blockIdx.x, h = blockIdx.y, bhl = blockIdx.z;
  const int bz = bz0 + bhl;
  const int dphys = h * 64 + g * 4 + w;
  const float aa = alpha_base[h] * alpha[bz];
  const float ps = phase_shift[h];
  const float wq0 = W_in[dphys], wq1 = W_in[1024 + dphys], wq2 = W_in[2048 + dphys], wq3 = W_in[3072 + dphys];
  const float bi = b_in[dphys];
  const float* xb = x + (size_t)bz * 4096 * 4;
  const int base = w * 2048;
  #pragma unroll
  for (int i = 0; i < 32; ++i) {
    int m = i * 64 + l;
    float4 xa = *(const float4*)(xb + (size_t)(2 * m) * 4);
    float4 xc = *(const float4*)(xb + (size_t)(2 * m + 1) * 4);
    float z0 = fmaf(xa.x, wq0, fmaf(xa.y, wq1, fmaf(xa.z, wq2, fmaf(xa.w, wq3, bi))));
    float z1 = fmaf(xc.x, wq0, fmaf(xc.y, wq1, fmaf(xc.z, wq2, fmaf(xc.w, wq3, bi))));
    fb[base + m] = make_float2(z0, z1);
  }
  __syncthreads();
  for (int st = 0; st < 11; ++st) {
    int hl = 10 - st;
    int half = 1 << hl;
    float invL = 1.0f / (float)(half << 1);
    #pragma unroll
    for (int u = 0; u < 16; ++u) {
      int bf = u * 64 + l;
      int blk = bf >> hl, tt = bf & (half - 1);
      int i1 = base + (blk << (hl + 1)) + tt;
      float2 a0 = fb[i1], b0 = fb[i1 + half];
      float sn, cs;
      __sincosf(-6.28318530717958647692f * (float)tt * invL, &sn, &cs);
      fb[i1] = make_float2(a0.x + b0.x, a0.y + b0.y);
      fb[i1 + half] = cmulf(make_float2(a0.x - b0.x, a0.y - b0.y), make_float2(cs, sn));
    }
    __syncthreads();
  }
  #pragma unroll
  for (int i = 0; i < 17; ++i) {
    int k = i * 64 + l;
    if (k > 1024) continue;
    if (k == 0) {
      float2 Z0 = fb[base];
      float X0 = Z0.x + Z0.y;
      float XM = Z0.x - Z0.y;
      float g0 = cosf(fmaf(aa, gelu[0], ps));
      float gM = cosf(fmaf(aa, gelu[2048], ps));
      float Y0 = g0 * X0, YM = gM * XM;
      fb[base] = make_float2(0.5f * (Y0 + YM), 0.5f * (Y0 - YM));
    } else if (k == 1024) {
      float2 Z = fb[base + 1];
      float gk = cosf(fmaf(aa, gelu[1024], ps));
      fb[base + 1] = make_float2(gk * Z.x, gk * Z.y);
    } else {
      int p1 = (int)(__brev((unsigned)k) >> 21);
      int p2 = (int)(__brev((unsigned)(2048 - k)) >> 21);
      float2 Zk = fb[base + p1], Zm = fb[base + p2];
      float2 E = make_float2(0.5f * (Zk.x + Zm.x), 0.5f * (Zk.y - Zm.y));
      float2 A = make_float2(Zk.x - Zm.x, Zk.y + Zm.y);
      float2 O = make_float2(0.5f * A.y, -0.5f * A.x);
      float sn, cs;
      __sincosf(-3.14159265358979323846f * (float)k * (1.0f / 2048.0f), &sn, &cs);
      float2 U = cmulf(make_float2(cs, sn), O);
      float2 Xk = make_float2(E.x + U.x, E.y + U.y);
      float2 Xm = make_float2(E.x - U.x, -(E.y - U.y));
      float gk = cosf(fmaf(aa, gelu[k], ps));
      float gm = cosf(fmaf(aa, gelu[2048 - k], ps));
      float2 Yk = make_float2(gk * Xk.x, gk * Xk.y);
      float2 Ym = make_float2(gm * Xm.x, gm * Xm.y);
      float2 Ep = make_float2(0.5f * (Yk.x + Ym.x), 0.5f * (Yk.y - Ym.y));
      float2 Aq = make_float2(0.5f * (Yk.x - Ym.x), 0.5f * (Yk.y + Ym.y));
      float2 Op = cmulf(make_float2(cs, -sn), Aq);
      fb[base + p1] = make_float2(Ep.x - Op.y, Ep.y + Op.x);
      fb[base + p2] = make_float2(Ep.x + Op.y, -Ep.y + Op.x);
    }
  }
  __syncthreads();
  for (int st = 0; st < 11; ++st) {
    int half = 1 << st;
    float invL = 1.0f / (float)(half << 1);
    #pragma unroll
    for (int u = 0; u < 16; ++u) {
      int bf = u * 64 + l;
      int blk = bf >> st, tt = bf & (half - 1);
      int i1 = base + (blk << (st + 1)) + tt;
      float2 a0 = fb[i1], b0 = fb[i1 + half];
      float sn, cs;
      __sincosf(6.28318530717958647692f * (float)tt * invL, &sn, &cs);
      float2 tb = cmulf(b0, make_float2(cs, sn));
      fb[i1] = make_float2(a0.x + tb.x, a0.y + tb.y);
      fb[i1 + half] = make_float2(a0.x - tb.x, a0.y - tb.y);
    }
    __syncthreads();
  }
  uint32* row = xfp + ((size_t)bhl * 1024 + dphys) * 4096;
  const float sc = 1.0f / 2048.0f;
  #pragma unroll
  for (int i = 0; i < 32; ++i) {
    int m = i * 64 + l;
    float2 v = fb[base + m];
    uint2 pv;
    pv.x = packhl(v.x * sc);
    pv.y = packhl(v.y * sc);
    *(uint2*)(row + 2 * m) = pv;
  }
}

// ---------------- split-precision GEMM: C[16384x1024] = A*W, A from packed [bh][d][s] ---------
// A staged with in-LDS transpose (XOR swizzle); acc += ah*bh + ah*bl + al*bh.
__global__ __launch_bounds__(256) void kx_gemm(const uint32* __restrict__ XF,
    const uint32* __restrict__ W2, float* __restrict__ C) {
  __shared__ uint32 As[128 * 64];   // [s][d^swz]
  __shared__ uint32 Bs[128 * 64];   // [n][d^swz]
  const int t = threadIdx.x, l = t & 63;
  const int w = t >> 6, wm = w >> 1, wn = w & 1;
  const int id = blockIdx.x;
  const int wg = (id & 7) * 128 + (id >> 3);        // XCD-contiguous bm chunks
  const int bm = wg >> 3, bn = wg & 7;
  const int bh = bm >> 5;
  const int s0 = (bm & 31) * 128;
  const int fr = l & 15, fko = (l >> 4) * 8;
  const int ar = t >> 5;             // 0..7
  const int ac = (t & 31) * 4;       // s col (4 consecutive)
  const int br = t >> 4;             // 0..15
  const int bc = (t & 15) * 4;       // d col (4 consecutive)
  const uint32* abase = XF + ((size_t)(bh * 1024)) * 4096 + s0;
  const uint32* bbase = W2 + (size_t)(bn * 128) * 1024;
  f32x4 acc[4][4];
  #pragma unroll
  for (int m = 0; m < 4; ++m)
    #pragma unroll
    for (int n = 0; n < 4; ++n) acc[m][n] = (f32x4){0.f, 0.f, 0.f, 0.f};
  uint4 ra[8], rb[8];
  #pragma unroll
  for (int i = 0; i < 8; ++i) {
    ra[i] = *(const uint4*)(abase + (size_t)(i * 8 + ar) * 4096 + ac);
    rb[i] = *(const uint4*)(bbase + (size_t)(i * 16 + br) * 1024 + bc);
  }
  #pragma unroll
  for (int i = 0; i < 8; ++i) {
    int r = i * 8 + ar;
    #pragma unroll
    for (int j = 0; j < 4; ++j) {
      int s = ac + j;
      As[s * 64 + (r ^ (((s >> 2) & 15) << 2))] = ((const uint32*)&ra[i])[j];
    }
    int n = i * 16 + br;
    *(uint4*)&Bs[n * 64 + (bc ^ ((n & 15) << 2))] = rb[i];
  }
  __syncthreads();
  for (int kt = 0; kt < 16; ++kt) {
    if (kt + 1 < 16) {
      #pragma unroll
      for (int i = 0; i < 8; ++i) {
        ra[i] = *(const uint4*)(abase + (size_t)((kt + 1) * 64 + i * 8 + ar) * 4096 + ac);
        rb[i] = *(const uint4*)(bbase + (size_t)(i * 16 + br) * 1024 + (kt + 1) * 64 + bc);
      }
    }
    #pragma unroll
    for (int kk = 0; kk < 2; ++kk) {
      bf16x8 ah[4], al[4], bh_[4], bl_[4];
      const int d0 = kk * 32 + fko;
      #pragma unroll
      for (int m = 0; m < 4; ++m) {
        int s = wm * 64 + m * 16 + fr;
        int X = ((s >> 2) & 15) << 2;
        uint4 q0 = *(const uint4*)&As[s * 64 + (d0 ^ X)];
        uint4 q1 = *(const uint4*)&As[s * 64 + ((d0 + 4) ^ X)];
        ah[m] = mkfrag((q0.x & 0xFFFFu) | (q0.y << 16), (q0.z & 0xFFFFu) | (q0.w << 16),
                       (q1.x & 0xFFFFu) | (q1.y << 16), (q1.z & 0xFFFFu) | (q1.w << 16));
        al[m] = mkfrag((q0.x >> 16) | (q0.y & 0xFFFF0000u), (q0.z >> 16) | (q0.w & 0xFFFF0000u),
                       (q1.x >> 16) | (q1.y & 0xFFFF0000u), (q1.z >> 16) | (q1.w & 0xFFFF0000u));
      }
      #pragma unroll
      for (int n = 0; n < 4; ++n) {
        int nn = wn * 64 + n * 16 + fr;
        int X = (nn & 15) << 2;
        uint4 q0 = *(const uint4*)&Bs[nn * 64 + (d0 ^ X)];
        uint4 q1 = *(const uint4*)&Bs[nn * 64 + ((d0 + 4) ^ X)];
        bh_[n] = mkfrag((q0.x & 0xFFFFu) | (q0.y << 16), (q0.z & 0xFFFFu) | (q0.w << 16),
                        (q1.x & 0xFFFFu) | (q1.y << 16), (q1.z & 0xFFFFu) | (q1.w << 16));
        bl_[n] = mkfrag((q0.x >> 16) | (q0.y & 0xFFFF0000u), (q0.z >> 16) | (q0.w & 0xFFFF0000u),
                        (q1.x >> 16) | (q1.y & 0xFFFF0000u), (q1.z >> 16) | (q1.w & 0xFFFF0000u));
      }
      #pragma unroll
      for (int m = 0; m < 4; ++m)
        #pragma unroll
        for (int n = 0; n < 4; ++n) {
          acc[m][n] = __builtin_amdgcn_mfma_f32_16x16x32_bf16(ah[m], bh_[n], acc[m][n], 0, 0, 0);
          acc[m][n] = __builtin_amdgcn_mfma_f32_16x16x32_bf16(ah[m], bl_[n], acc[m][n], 0, 0, 0);
          acc[m][n] = __builtin_amdgcn_mfma_f32_16x16x32_bf16(al[m], bh_[n], acc[m][n], 0, 0, 0);
        }
    }
    __syncthreads();
    if (kt + 1 < 16) {
      #pragma unroll
      for (int i = 0; i < 8; ++i) {
        int r = i * 8 + ar;
        #pragma unroll
        for (int j = 0; j < 4; ++j) {
          int s = ac + j;
          As[s * 64 + (r ^ (((s >> 2) & 15) << 2))] = ((const uint32*)&ra[i])[j];
        }
        int n = i * 16 + br;
        *(uint4*)&Bs[n * 64 + (bc ^ ((n & 15) << 2))] = rb[i];
      }
    }
    __syncthreads();
  }
  const int rl4 = (l >> 4) * 4;
  #pragma unroll
  for (int m = 0; m < 4; ++m) {
    int row = bm * 128 + wm * 64 + m * 16 + rl4;
    #pragma unroll
    for (int n = 0; n < 4; ++n) {
      int colg = bn * 128 + wn * 64 + n * 16 + (l & 15);
      #pragma unroll
      for (int e = 0; e < 4; ++e)
        C[(size_t)(row + e) * 1024 + colg] = acc[m][n][e];
    }
  }
}

// ---------------- tail: LN(xp+out) -> @W_out -> quat chain per row ----------------------------
DEV float wred64(float v) {
  #pragma unroll
  for (int m = 32; m; m >>= 1) v += __shfl_xor(v, m);
  return v;
}
DEV float4 qmul4(float4 a, float4 b) {
  return make_float4(
    a.x * b.x - a.y * b.y - a.z * b.z - a.w * b.w,
    a.x * b.y + a.y * b.x + a.z * b.w - a.w * b.z,
    a.x * b.z - a.y * b.w + a.z * b.x + a.w * b.y,
    a.x * b.w + a.y * b.z - a.z * b.y + a.w * b.x);
}
DEV float4 ln4q(float4 v, const float* g, const float* b) {
  float m = 0.25f * (v.x + v.y + v.z + v.w);
  float a0 = v.x - m, a1 = v.y - m, a2 = v.z - m, a3 = v.w - m;
  float var = 0.25f * (a0 * a0 + a1 * a1 + a2 * a2 + a3 * a3);
  float rs = 1.0f / sqrtf(var + 1e-5f);
  return make_float4(a0 * rs * g[0] + b[0], a1 * rs * g[1] + b[1],
                     a2 * rs * g[2] + b[2], a3 * rs * g[3] + b[3]);
}
DEV float4 qne(float4 q) {
  float n = sqrtf(q.x * q.x + q.y * q.y + q.z * q.z + q.w * q.w) + 1e-8f;
  float r = 1.0f / n;
  return make_float4(q.x * r, q.y * r, q.z * r, q.w * r);
}
DEV float gelu1(float v) { return 0.5f * v * (1.0f + erff(v * 0.70710678118654752440f)); }

__global__ __launch_bounds__(256) void kx_tail(const float* __restrict__ G,
    const float* __restrict__ x, const float* __restrict__ W_in, const float* __restrict__ b_in,
    const float* __restrict__ b_attn, const float* __restrict__ lng, const float* __restrict__ lnb,
    const float* __restrict__ W_out, const float* __restrict__ b_out,
    const float* __restrict__ thL, const float* __restrict__ thR,
    const float* __restrict__ Wf1, const float* __restrict__ bff1,
    const float* __restrict__ Wf2, const float* __restrict__ bff2,
    const float* __restrict__ n1g, const float* __restrict__ n1b,
    const float* __restrict__ n2g, const float* __restrict__ n2b,
    const float* __restrict__ n3g, const float* __restrict__ n3b,
    float* __restrict__ out, int rows0) {
  const int l = threadIdx.x & 63, w = threadIdx.x >> 6;
  const size_t rl = (size_t)blockIdx.x * 4 + w;
  const size_t rg = rows0 + rl;
  const float4 x4 = *(const float4*)(x + rg * 4);
  float4 tv[4];
  float lsum = 0.f;
  #pragma unroll
  for (int j = 0; j < 4; ++j) {
    int dd = j * 256 + l * 4;
    float4 g4 = *(const float4*)(G + rl * 1024 + dd);
    float4 w0 = *(const float4*)(W_in + dd);
    float4 w1 = *(const float4*)(W_in + 1024 + dd);
    float4 w2 = *(const float4*)(W_in + 2048 + dd);
    float4 w3 = *(const float4*)(W_in + 3072 + dd);
    float4 bi = *(const float4*)(b_in + dd);
    float4 ba = *(const float4*)(b_attn + dd);
    float4 o;
    o.x = g4.x + bi.x + ba.x + x4.x * w0.x + x4.y * w1.x + x4.z * w2.x + x4.w * w3.x;
    o.y = g4.y + bi.y + ba.y + x4.x * w0.y + x4.y * w1.y + x4.z * w2.y + x4.w * w3.y;
    o.z = g4.z + bi.z + ba.z + x4.x * w0.z + x4.y * w1.z + x4.z * w2.z + x4.w * w3.z;
    o.w = g4.w + bi.w + ba.w + x4.x * w0.w + x4.y * w1.w + x4.z * w2.w + x4.w * w3.w;
    tv[j] = o;
    lsum += o.x + o.y + o.z + o.w;
  }
  const float mean = wred64(lsum) * (1.0f / 1024.0f);
  float vsum = 0.f;
  #pragma unroll
  for (int j = 0; j < 4; ++j) {
    float a0 = tv[j].x - mean, a1 = tv[j].y - mean, a2 = tv[j].z - mean, a3 = tv[j].w - mean;
    vsum += a0 * a0 + a1 * a1 + a2 * a2 + a3 * a3;
  }
  const float rstd = 1.0f / sqrtf(wred64(vsum) * (1.0f / 1024.0f) + 1e-5f);
  float4 aq = make_float4(0.f, 0.f, 0.f, 0.f);
  #pragma unroll
  for (int j = 0; j < 4; ++j) {
    int dd = j * 256 + l * 4;
    float4 gg = *(const float4*)(lng + dd);
    float4 bb = *(const float4*)(lnb + dd);
    float av[4];
    av[0] = (tv[j].x - mean) * rstd * gg.x + bb.x;
    av[1] = (tv[j].y - mean) * rstd * gg.y + bb.y;
    av[2] = (tv[j].z - mean) * rstd * gg.z + bb.z;
    av[3] = (tv[j].w - mean) * rstd * gg.w + bb.w;
    #pragma unroll
    for (int e = 0; e < 4; ++e) {
      float4 wr = *(const float4*)(W_out + (size_t)(dd + e) * 4);
      aq.x = fmaf(av[e], wr.x, aq.x);
      aq.y = fmaf(av[e], wr.y, aq.y);
      aq.z = fmaf(av[e], wr.z, aq.z);
      aq.w = fmaf(av[e], wr.w, aq.w);
    }
  }
  aq.x = wred64(aq.x) + b_out[0];
  aq.y = wred64(aq.y) + b_out[1];
  aq.z = wred64(aq.z) + b_out[2];
  aq.w = wred64(aq.w) + b_out[3];
  float4 q1 = make_float4(x4.x + aq.x, x4.y + aq.y, x4.z + aq.z, x4.w + aq.w);
  float4 hq = qne(ln4q(q1, n1g, n1b));
  float4 o = hq;
  #pragma unroll
  for (int it = 0; it < 4; ++it) {
    float sl0, cl0, sl1, cl1, sl2, cl2;
    sincosf(0.5f * thL[it * 3 + 0], &sl0, &cl0);
    sincosf(0.5f * thL[it * 3 + 1], &sl1, &cl1);
    sincosf(0.5f * thL[it * 3 + 2], &sl2, &cl2);
    float4 qL = qne(make_float4(cl0 * cl1 * cl2, sl0 * cl1 * cl2, cl0 * sl1 * cl2, cl0 * cl1 * sl2));
    float sr0, cr0, sr1, cr1, sr2, cr2;
    sincosf(0.5f * thR[it * 3 + 0], &sr0, &cr0);
    sincosf(0.5f * thR[it * 3 + 1], &sr1, &cr1);
    sincosf(0.5f * thR[it * 3 + 2], &sr2, &cr2);
    float4 qR = qne(make_float4(cr0 * cr1 * cr2, sr0 * cr1 * cr2, cr0 * sr1 * cr2, cr0 * cr1 * sr2));
    float4 qRc = make_float4(qR.x, -qR.y, -qR.z, -qR.w);
    o = qmul4(qmul4(qL, o), qRc);
    o = qne(o);
  }
  float4 h2 = qne(ln4q(make_float4(hq.x + o.x, hq.y + o.y, hq.z + o.z, hq.w + o.w), n2g, n2b));
  float4 ffv = make_float4(bff2[0], bff2[1], bff2[2], bff2[3]);
  #pragma unroll
  for (int k = 0; k < 16; ++k) {
    float uv = bff1[k] + h2.x * Wf1[k] + h2.y * Wf1[16 + k] + h2.z * Wf1[32 + k] + h2.w * Wf1[48 + k];
    uv = gelu1(uv);
    ffv.x = fmaf(uv, Wf2[k * 4 + 0], ffv.x);
    ffv.y = fmaf(uv, Wf2[k * 4 + 1], ffv.y);
    ffv.z = fmaf(uv, Wf2[k * 4 + 2], ffv.z);
    ffv.w = fmaf(uv, Wf2[k * 4 + 3], ffv.w);
  }
  float4 h3 = qne(ln4q(make_float4(h2.x + ffv.x, h2.y + ffv.y, h2.z + ffv.z, h2.w + ffv.w), n3g, n3b));
  if (l == 0) *(float4*)(out + rg * 4) = h3;
}

extern "C" void kernel_launch(void* const* d_in, const int* in_sizes, int n_in,
                              void* d_out, int out_size, void* d_ws, size_t ws_size,
                              hipStream_t stream) {
  (void)in_sizes; (void)n_in; (void)out_size;
  const float* x      = (const float*)d_in[0];
  const float* W_in   = (const float*)d_in[1];
  const float* b_in   = (const float*)d_in[2];
  const float* abase  = (const float*)d_in[3];
  const float* pshift = (const float*)d_in[4];
  const float* Wattn  = (const float*)d_in[5];
  const float* battn  = (const float*)d_in[6];
  const float* lng    = (const float*)d_in[7];
  const float* lnb    = (const float*)d_in[8];
  const float* Wout   = (const float*)d_in[9];
  const float* bout   = (const float*)d_in[10];
  const float* thL    = (const float*)d_in[11];
  const float* thR    = (const float*)d_in[12];
  const float* Wf1    = (const float*)d_in[13];
  const float* bff1   = (const float*)d_in[14];
  const float* Wf2    = (const float*)d_in[15];
  const float* bff2   = (const float*)d_in[16];
  const float* n1g    = (const float*)d_in[17];
  const float* n1b    = (const float*)d_in[18];
  const float* n2g    = (const float*)d_in[19];
  const float* n2b    = (const float*)d_in[20];
  const float* n3g    = (const float*)d_in[21];
  const float* n3b    = (const float*)d_in[22];

  if (ws_size < (size_t)138459204) return;  // ~132 MiB
  char* ws = (char*)d_ws;
  float2* Zmid  = (float2*)ws;                       // 128MiB (fractal only)
  uint32* XFp   = (uint32*)ws;                       // 64MiB per half (packed filter out)
  float*  Cout  = (float*)(ws + 67108864);           // 64MiB per half (gemm out)
  uint32* W2    = (uint32*)(ws + 134217728);         // 4MiB packed W^T
  float* partials = (float*)(ws + 138412032);        // 32KB
  float* sparts   = (float*)(ws + 138444800);        // 6KB
  float* alphaw   = (float*)(ws + 138450944);        // 32B
  float* geluw    = (float*)(ws + 138451008);        // 8.2KB

  kx_fr_pass1<<<dim3(256, 8), 512, 0, stream>>>(x, W_in, b_in, Zmid);
  kx_fr_pass2<<<dim3(512, 8), 256, 0, stream>>>(Zmid, partials, sparts);
  kx_finalize<<<1, 512, 0, stream>>>(partials, sparts, alphaw, geluw);
  kx_wt<<<dim3(16, 16), 256, 0, stream>>>(Wattn, W2);
  for (int half = 0; half < 2; ++half) {
    kx_filter<<<dim3(16, 16, 4), 256, 0, stream>>>(x, W_in, b_in, alphaw, geluw,
                                                   abase, pshift, XFp, half * 4);
    kx_gemm<<<1024, 256, 0, stream>>>(XFp, W2, Cout);
    kx_tail<<<4096, 256, 0, stream>>>(Cout, x, W_in, b_in, battn, lng, lnb, Wout, bout,
                                      thL, thR, Wf1, bff1, Wf2, bff2,
                                      n1g, n1b, n2g, n2b, n3g, n3b,
                                      (float*)d_out, half * 16384);
  }
}

// Round 3
// 982.710 us; speedup vs baseline: 1.0358x; 1.0358x over previous
//
#include <hip/hip_runtime.h>
#include <hip/hip_bf16.h>
#include <math.h>

// PsiQRH block, MI355X. B=8 S=4096 QD=4 DM=1024 H=16 HD=64.
// Round 3: kx_gemm fixes — LDS-staged coalesced epilogue (WRITE_SIZE 446->66MiB),
// better A swizzle (bank conflicts), v_perm hi/lo unpack (VALU).

#define DEV static __device__ __forceinline__
typedef unsigned int uint32;

typedef __attribute__((ext_vector_type(8))) short bf16x8;
typedef __attribute__((ext_vector_type(4))) float f32x4;

DEV float2 cmulf(float2 a, float2 b) {
  return make_float2(a.x * b.x - a.y * b.y, a.x * b.y + a.y * b.x);
}
DEV unsigned short f2bf(float f) {
  __hip_bfloat16 h = __float2bfloat16(f);
  return *reinterpret_cast<unsigned short*>(&h);
}
DEV uint32 packhl(float f) {
  unsigned short h = f2bf(f);
  uint32 hb = ((uint32)h) << 16;
  float fh = __uint_as_float(hb);
  unsigned short lo = f2bf(f - fh);
  return (uint32)h | (((uint32)lo) << 16);
}
DEV bf16x8 mkfrag(uint32 a, uint32 b, uint32 c, uint32 d) {
  union { uint4 u; bf16x8 v; } x;
  x.u = make_uint4(a, b, c, d);
  return x.v;
}
// dst = (lo word of a) | (lo word of b)<<16  /  (hi word of a) | (hi word of b high)
DEV uint32 plo(uint32 a, uint32 b) { return __builtin_amdgcn_perm(b, a, 0x05040100u); }
DEV uint32 phi(uint32 a, uint32 b) { return __builtin_amdgcn_perm(b, a, 0x07060302u); }

// ---------------- fractal pass 1: 1024-pt FFTs over a (z[n]=xp[2n]+i*xp[2n+1], n=2048a+b) ----
__global__ __launch_bounds__(512) void kx_fr_pass1(const float* __restrict__ x,
    const float* __restrict__ W_in, const float* __restrict__ b_in,
    float2* __restrict__ zmid) {
  __shared__ float2 fb[8 * 1024];
  const int t = threadIdx.x, l = t & 63, w = t >> 6;
  const int btile = blockIdx.x, bz = blockIdx.y;
  const int bcol = btile * 8 + w;
  const int d = 2 * (bcol & 511);
  const int soff = bcol >> 9;
  const float w00 = W_in[d],     w10 = W_in[1024 + d], w20 = W_in[2048 + d], w30 = W_in[3072 + d];
  const float w01 = W_in[d + 1], w11 = W_in[1025 + d], w21 = W_in[2049 + d], w31 = W_in[3073 + d];
  const float bi0 = b_in[d], bi1 = b_in[d + 1];
  const float* xb = x + (size_t)bz * 4096 * 4;
  #pragma unroll
  for (int i = 0; i < 16; ++i) {
    int a = i * 64 + l;
    int s = 4 * a + soff;
    float4 xv = *(const float4*)(xb + (size_t)s * 4);
    float z0 = fmaf(xv.x, w00, fmaf(xv.y, w10, fmaf(xv.z, w20, fmaf(xv.w, w30, bi0))));
    float z1 = fmaf(xv.x, w01, fmaf(xv.y, w11, fmaf(xv.z, w21, fmaf(xv.w, w31, bi1))));
    fb[w * 1024 + a] = make_float2(z0, z1);
  }
  __syncthreads();
  for (int st = 0; st < 10; ++st) {
    int hl = 9 - st;
    int half = 1 << hl;
    float invL = 1.0f / (float)(half << 1);
    #pragma unroll
    for (int u = 0; u < 8; ++u) {
      int bf = u * 64 + l;
      int blk = bf >> hl, tt = bf & (half - 1);
      int i1 = w * 1024 + (blk << (hl + 1)) + tt;
      float2 a0 = fb[i1], b0 = fb[i1 + half];
      float sn, cs;
      __sincosf(-6.28318530717958647692f * (float)tt * invL, &sn, &cs);
      fb[i1] = make_float2(a0.x + b0.x, a0.y + b0.y);
      fb[i1 + half] = cmulf(make_float2(a0.x - b0.x, a0.y - b0.y), make_float2(cs, sn));
    }
    __syncthreads();
  }
  float2* dst = zmid + (size_t)bz * (1024 * 2048);
  #pragma unroll
  for (int i = 0; i < 16; ++i) {
    int idx = i * 512 + t;
    int w8 = idx & 7, cnat = idx >> 3;
    float2 v = fb[w8 * 1024 + (int)(__brev((unsigned)cnat) >> 22)];
    dst[(size_t)cnat * 2048 + btile * 8 + w8] = v;
  }
}

DEV float block_reduce256(float* red, int t, float v) {
  red[t] = v; __syncthreads();
  for (int s = 128; s; s >>= 1) { if (t < s) red[t] += red[t + s]; __syncthreads(); }
  float r = red[0]; __syncthreads();
  return r;
}

// ---------------- fractal pass 2: twiddle + 2048-pt FFT over b, untwist, log-log moments -----
__global__ __launch_bounds__(256) void kx_fr_pass2(const float2* __restrict__ zmid,
    float* __restrict__ partials, float* __restrict__ sparts) {
  __shared__ float2 fb[2 * 2048];
  __shared__ float red[256];
  const int t = threadIdx.x, l = t & 63, w = t >> 6;
  const int cg = blockIdx.x, bz = blockIdx.y;
  const int col = w >> 1;
  const int l128 = (w & 1) * 64 + l;
  const int c = (cg == 0) ? (col ? 512 : 0) : (col ? (1024 - cg) : cg);
  const float2* src = zmid + ((size_t)bz * 1024 + c) * 2048;
  #pragma unroll
  for (int i = 0; i < 16; ++i) {
    int bb = i * 128 + l128;
    float2 z = src[bb];
    float fr = (float)(bb * c) * (1.0f / 2097152.0f);
    float sn, cs;
    __sincosf(-6.28318530717958647692f * fr, &sn, &cs);
    fb[col * 2048 + bb] = cmulf(z, make_float2(cs, sn));
  }
  __syncthreads();
  for (int st = 0; st < 11; ++st) {
    int hl = 10 - st;
    int half = 1 << hl;
    float invL = 1.0f / (float)(half << 1);
    #pragma unroll
    for (int u = 0; u < 8; ++u) {
      int bf = u * 128 + l128;
      int blk = bf >> hl, tt = bf & (half - 1);
      int i1 = col * 2048 + (blk << (hl + 1)) + tt;
      float2 a0 = fb[i1], b0 = fb[i1 + half];
      float sn, cs;
      __sincosf(-6.28318530717958647692f * (float)tt * invL, &sn, &cs);
      fb[i1] = make_float2(a0.x + b0.x, a0.y + b0.y);
      fb[i1 + half] = cmulf(make_float2(a0.x - b0.x, a0.y - b0.y), make_float2(cs, sn));
    }
    __syncthreads();
  }
  const int mcol = (cg == 0) ? col : (1 - col);
  float t0 = 0.f, t1 = 0.f, s0 = 0.f, s1 = 0.f, s2 = 0.f;
  #pragma unroll
  for (int i = 0; i < 16; ++i) {
    int dd = i * 128 + l128;
    int md = (c == 0) ? ((2048 - dd) & 2047) : (2047 - dd);
    float2 Zk = fb[col * 2048 + (int)(__brev((unsigned)dd) >> 21)];
    float2 Zm = fb[mcol * 2048 + (int)(__brev((unsigned)md) >> 21)];
    float2 E = make_float2(0.5f * (Zk.x + Zm.x), 0.5f * (Zk.y - Zm.y));
    float2 A = make_float2(Zk.x - Zm.x, Zk.y + Zm.y);
    float2 O = make_float2(0.5f * A.y, -0.5f * A.x);
    int k = c + (dd << 10);
    float fr = (float)k * (1.0f / 4194304.0f);
    float sn, cs;
    __sincosf(-6.28318530717958647692f * fr, &sn, &cs);
    float2 U = cmulf(make_float2(cs, sn), O);
    float Xr = E.x + U.x, Xi = E.y + U.y;
    float P = Xr * Xr + Xi * Xi;
    if (fr > 0.01f && fr < 0.5f) {
      float lp = logf(P + 1e-10f);
      float lk = logf(fr + 1e-10f);
      t0 += lp; t1 += lk * lp;
      s0 += 1.0f; s1 += lk; s2 += lk * lk;
    }
  }
  float T0 = block_reduce256(red, t, t0);
  float T1 = block_reduce256(red, t, t1);
  if (t == 0) {
    partials[((size_t)bz * 512 + cg) * 2 + 0] = T0;
    partials[((size_t)bz * 512 + cg) * 2 + 1] = T1;
  }
  if (bz == 0) {
    float S0 = block_reduce256(red, t, s0);
    float S1 = block_reduce256(red, t, s1);
    float S2 = block_reduce256(red, t, s2);
    if (t == 0) { sparts[cg * 3] = S0; sparts[cg * 3 + 1] = S1; sparts[cg * 3 + 2] = S2; }
  }
}

DEV float block_reduce512(float* sh, int t, float v) {
  sh[t] = v; __syncthreads();
  for (int s = 256; s; s >>= 1) { if (t < s) sh[t] += sh[t + s]; __syncthreads(); }
  float r = sh[0]; __syncthreads();
  return r;
}

// ---------------- finalize: alpha[b]; gelu_k table ---------------------------------------------
__global__ __launch_bounds__(512) void kx_finalize(const float* __restrict__ partials,
    const float* __restrict__ sparts, float* __restrict__ alpha, float* __restrict__ gelu) {
  __shared__ float sh[512];
  __shared__ float lk[4096];
  const int t = threadIdx.x;
  float S0 = block_reduce512(sh, t, sparts[t * 3 + 0]);
  float S1 = block_reduce512(sh, t, sparts[t * 3 + 1]);
  float S2 = block_reduce512(sh, t, sparts[t * 3 + 2]);
  float mk = S1 / S0;
  float var = S2 - mk * S1;
  for (int b = 0; b < 8; ++b) {
    float T0 = block_reduce512(sh, t, partials[((size_t)b * 512 + t) * 2 + 0]);
    float T1 = block_reduce512(sh, t, partials[((size_t)b * 512 + t) * 2 + 1]);
    if (t == 0) {
      float cov = T1 - mk * T0;
      float beta = -cov / (var + 1e-10f);
      float D = fminf(fmaxf((3.0f - beta) * 0.5f, 0.5f), 1.5f);
      alpha[b] = fminf(fmaxf(1.0f + 0.8f * (D - 1.0f), 0.1f), 3.0f);
    }
  }
  for (int s = t; s < 4096; s += 512) {
    int m = (s < 2048) ? s : (4096 - s);
    lk[s] = logf((float)m * (1.0f / 4096.0f) + 1e-8f);
  }
  __syncthreads();
  float ls = 0.f;
  for (int s = t; s < 4096; s += 512) ls += lk[s];
  float mean = block_reduce512(sh, t, ls) * (1.0f / 4096.0f);
  float vs = 0.f;
  for (int s = t; s < 4096; s += 512) { float dv = lk[s] - mean; vs += dv * dv; }
  float sd = sqrtf(block_reduce512(sh, t, vs) * (1.0f / 4095.0f));
  for (int k = t; k < 2049; k += 512) {
    float xn = (lk[k] - mean) / (sd + 1e-8f);
    gelu[k] = 0.5f * xn * (1.0f + erff(xn * 0.70710678118654752440f));
  }
}

// ---------------- W_attn_out transpose -> packed hi/lo bf16 [n][d] ----------------------------
__global__ __launch_bounds__(256) void kx_wt(const float* __restrict__ W, uint32* __restrict__ Wt) {
  __shared__ float tile[64][65];
  const int t = threadIdx.x;
  const int nt = blockIdx.x, dt = blockIdx.y;
  #pragma unroll
  for (int i = 0; i < 16; ++i) {
    int idx = i * 256 + t;
    int r = idx >> 6, cc = idx & 63;
    tile[r][cc] = W[(size_t)(dt * 64 + r) * 1024 + nt * 64 + cc];
  }
  __syncthreads();
  #pragma unroll
  for (int i = 0; i < 16; ++i) {
    int idx = i * 256 + t;
    int r = idx >> 6, cc = idx & 63;
    Wt[(size_t)(nt * 64 + r) * 1024 + dt * 64 + cc] = packhl(tile[cc][r]);
  }
}

// ---------------- spectral filter: irfft(rfft(xp)*cos(phase)) per (b,d), writes packed [bh][d][s]
__global__ __launch_bounds__(256) void kx_filter(const float* __restrict__ x,
    const float* __restrict__ W_in, const float* __restrict__ b_in,
    const float* __restrict__ alpha, const float* __restrict__ gelu,
    const float* __restrict__ alpha_base, const float* __restrict__ phase_shift,
    uint32* __restrict__ xfp, int bz0) {
  __shared__ float2 fb[4 * 2048];
  const int t = threadIdx.x, l = t & 63, w = t >> 6;
  const int g = blockIdx.x, h = blockIdx.y, bhl = blockIdx.z;
  const int bz = bz0 + bhl;
  const int dphys = h * 64 + g * 4 + w;
  const float aa = alpha_base[h] * alpha[bz];
  const float ps = phase_shift[h];
  const float wq0 = W_in[dphys], wq1 = W_in[1024 + dphys], wq2 = W_in[2048 + dphys], wq3 = W_in[3072 + dphys];
  const float bi = b_in[dphys];
  const float* xb = x + (size_t)bz * 4096 * 4;
  const int base = w * 2048;
  #pragma unroll
  for (int i = 0; i < 32; ++i) {
    int m = i * 64 + l;
    float4 xa = *(const float4*)(xb + (size_t)(2 * m) * 4);
    float4 xc = *(const float4*)(xb + (size_t)(2 * m + 1) * 4);
    float z0 = fmaf(xa.x, wq0, fmaf(xa.y, wq1, fmaf(xa.z, wq2, fmaf(xa.w, wq3, bi))));
    float z1 = fmaf(xc.x, wq0, fmaf(xc.y, wq1, fmaf(xc.z, wq2, fmaf(xc.w, wq3, bi))));
    fb[base + m] = make_float2(z0, z1);
  }
  __syncthreads();
  for (int st = 0; st < 11; ++st) {
    int hl = 10 - st;
    int half = 1 << hl;
    float invL = 1.0f / (float)(half << 1);
    #pragma unroll
    for (int u = 0; u < 16; ++u) {
      int bf = u * 64 + l;
      int blk = bf >> hl, tt = bf & (half - 1);
      int i1 = base + (blk << (hl + 1)) + tt;
      float2 a0 = fb[i1], b0 = fb[i1 + half];
      float sn, cs;
      __sincosf(-6.28318530717958647692f * (float)tt * invL, &sn, &cs);
      fb[i1] = make_float2(a0.x + b0.x, a0.y + b0.y);
      fb[i1 + half] = cmulf(make_float2(a0.x - b0.x, a0.y - b0.y), make_float2(cs, sn));
    }
    __syncthreads();
  }
  #pragma unroll
  for (int i = 0; i < 17; ++i) {
    int k = i * 64 + l;
    if (k > 1024) continue;
    if (k == 0) {
      float2 Z0 = fb[base];
      float X0 = Z0.x + Z0.y;
      float XM = Z0.x - Z0.y;
      float g0 = cosf(fmaf(aa, gelu[0], ps));
      float gM = cosf(fmaf(aa, gelu[2048], ps));
      float Y0 = g0 * X0, YM = gM * XM;
      fb[base] = make_float2(0.5f * (Y0 + YM), 0.5f * (Y0 - YM));
    } else if (k == 1024) {
      float2 Z = fb[base + 1];
      float gk = cosf(fmaf(aa, gelu[1024], ps));
      fb[base + 1] = make_float2(gk * Z.x, gk * Z.y);
    } else {
      int p1 = (int)(__brev((unsigned)k) >> 21);
      int p2 = (int)(__brev((unsigned)(2048 - k)) >> 21);
      float2 Zk = fb[base + p1], Zm = fb[base + p2];
      float2 E = make_float2(0.5f * (Zk.x + Zm.x), 0.5f * (Zk.y - Zm.y));
      float2 A = make_float2(Zk.x - Zm.x, Zk.y + Zm.y);
      float2 O = make_float2(0.5f * A.y, -0.5f * A.x);
      float sn, cs;
      __sincosf(-3.14159265358979323846f * (float)k * (1.0f / 2048.0f), &sn, &cs);
      float2 U = cmulf(make_float2(cs, sn), O);
      float2 Xk = make_float2(E.x + U.x, E.y + U.y);
      float2 Xm = make_float2(E.x - U.x, -(E.y - U.y));
      float gk = cosf(fmaf(aa, gelu[k], ps));
      float gm = cosf(fmaf(aa, gelu[2048 - k], ps));
      float2 Yk = make_float2(gk * Xk.x, gk * Xk.y);
      float2 Ym = make_float2(gm * Xm.x, gm * Xm.y);
      float2 Ep = make_float2(0.5f * (Yk.x + Ym.x), 0.5f * (Yk.y - Ym.y));
      float2 Aq = make_float2(0.5f * (Yk.x - Ym.x), 0.5f * (Yk.y + Ym.y));
      float2 Op = cmulf(make_float2(cs, -sn), Aq);
      fb[base + p1] = make_float2(Ep.x - Op.y, Ep.y + Op.x);
      fb[base + p2] = make_float2(Ep.x + Op.y, -Ep.y + Op.x);
    }
  }
  __syncthreads();
  for (int st = 0; st < 11; ++st) {
    int half = 1 << st;
    float invL = 1.0f / (float)(half << 1);
    #pragma unroll
    for (int u = 0; u < 16; ++u) {
      int bf = u * 64 + l;
      int blk = bf >> st, tt = bf & (half - 1);
      int i1 = base + (blk << (st + 1)) + tt;
      float2 a0 = fb[i1], b0 = fb[i1 + half];
      float sn, cs;
      __sincosf(6.28318530717958647692f * (float)tt * invL, &sn, &cs);
      float2 tb = cmulf(b0, make_float2(cs, sn));
      fb[i1] = make_float2(a0.x + tb.x, a0.y + tb.y);
      fb[i1 + half] = make_float2(a0.x - tb.x, a0.y - tb.y);
    }
    __syncthreads();
  }
  uint32* row = xfp + ((size_t)bhl * 1024 + dphys) * 4096;
  const float sc = 1.0f / 2048.0f;
  #pragma unroll
  for (int i = 0; i < 32; ++i) {
    int m = i * 64 + l;
    float2 v = fb[base + m];
    uint2 pv;
    pv.x = packhl(v.x * sc);
    pv.y = packhl(v.y * sc);
    *(uint2*)(row + 2 * m) = pv;
  }
}

// ---------------- split-precision GEMM: C[16384x1024] = A*W, A from packed [bh][d][s] ---------
DEV int aidx(int s, int d) { return s * 64 + (d ^ (((s + (s >> 2)) & 15) << 2)); }
DEV int bidx(int n, int d) { return n * 64 + (d ^ ((n & 15) << 2)); }

__global__ __launch_bounds__(256) void kx_gemm(const uint32* __restrict__ XF,
    const uint32* __restrict__ W2, float* __restrict__ C) {
  __shared__ uint32 sm[16384];           // 64KB: As[0..8191] Bs[8192..16383]; epilogue: f32 Cs[128][128]
  uint32* As = sm;
  uint32* Bs = sm + 8192;
  const int t = threadIdx.x, l = t & 63;
  const int w = t >> 6, wm = w >> 1, wn = w & 1;
  const int id = blockIdx.x;
  const int wg = (id & 7) * 128 + (id >> 3);        // XCD-contiguous bm chunks
  const int bm = wg >> 3, bn = wg & 7;
  const int bh = bm >> 5;
  const int s0 = (bm & 31) * 128;
  const int fr = l & 15, fko = (l >> 4) * 8;
  const int ar = t >> 5;             // 0..7  (d-row group)
  const int ac = (t & 31) * 4;       // s col (4 consecutive)
  const int br = t >> 4;             // 0..15
  const int bc = (t & 15) * 4;       // d col (4 consecutive)
  const uint32* abase = XF + ((size_t)(bh * 1024)) * 4096 + s0;
  const uint32* bbase = W2 + (size_t)(bn * 128) * 1024;
  f32x4 acc[4][4];
  #pragma unroll
  for (int m = 0; m < 4; ++m)
    #pragma unroll
    for (int n = 0; n < 4; ++n) acc[m][n] = (f32x4){0.f, 0.f, 0.f, 0.f};
  uint4 ra[8], rb[8];
  #pragma unroll
  for (int i = 0; i < 8; ++i) {
    ra[i] = *(const uint4*)(abase + (size_t)(i * 8 + ar) * 4096 + ac);
    rb[i] = *(const uint4*)(bbase + (size_t)(i * 16 + br) * 1024 + bc);
  }
  #pragma unroll
  for (int i = 0; i < 8; ++i) {
    int r = i * 8 + ar;
    #pragma unroll
    for (int j = 0; j < 4; ++j) As[aidx(ac + j, r)] = ((const uint32*)&ra[i])[j];
    int n = i * 16 + br;
    *(uint4*)&Bs[bidx(n, bc)] = rb[i];
  }
  __syncthreads();
  for (int kt = 0; kt < 16; ++kt) {
    if (kt + 1 < 16) {
      #pragma unroll
      for (int i = 0; i < 8; ++i) {
        ra[i] = *(const uint4*)(abase + (size_t)((kt + 1) * 64 + i * 8 + ar) * 4096 + ac);
        rb[i] = *(const uint4*)(bbase + (size_t)(i * 16 + br) * 1024 + (kt + 1) * 64 + bc);
      }
    }
    #pragma unroll
    for (int kk = 0; kk < 2; ++kk) {
      bf16x8 ah[4], al[4], bh_[4], bl_[4];
      const int d0 = kk * 32 + fko;
      #pragma unroll
      for (int m = 0; m < 4; ++m) {
        int s = wm * 64 + m * 16 + fr;
        uint4 q0 = *(const uint4*)&As[aidx(s, d0)];
        uint4 q1 = *(const uint4*)&As[aidx(s, d0 + 4)];
        ah[m] = mkfrag(plo(q0.x, q0.y), plo(q0.z, q0.w), plo(q1.x, q1.y), plo(q1.z, q1.w));
        al[m] = mkfrag(phi(q0.x, q0.y), phi(q0.z, q0.w), phi(q1.x, q1.y), phi(q1.z, q1.w));
      }
      #pragma unroll
      for (int n = 0; n < 4; ++n) {
        int nn = wn * 64 + n * 16 + fr;
        uint4 q0 = *(const uint4*)&Bs[bidx(nn, d0)];
        uint4 q1 = *(const uint4*)&Bs[bidx(nn, d0 + 4)];
        bh_[n] = mkfrag(plo(q0.x, q0.y), plo(q0.z, q0.w), plo(q1.x, q1.y), plo(q1.z, q1.w));
        bl_[n] = mkfrag(phi(q0.x, q0.y), phi(q0.z, q0.w), phi(q1.x, q1.y), phi(q1.z, q1.w));
      }
      #pragma unroll
      for (int m = 0; m < 4; ++m)
        #pragma unroll
        for (int n = 0; n < 4; ++n) {
          acc[m][n] = __builtin_amdgcn_mfma_f32_16x16x32_bf16(ah[m], bh_[n], acc[m][n], 0, 0, 0);
          acc[m][n] = __builtin_amdgcn_mfma_f32_16x16x32_bf16(ah[m], bl_[n], acc[m][n], 0, 0, 0);
          acc[m][n] = __builtin_amdgcn_mfma_f32_16x16x32_bf16(al[m], bh_[n], acc[m][n], 0, 0, 0);
        }
    }
    __syncthreads();
    if (kt + 1 < 16) {
      #pragma unroll
      for (int i = 0; i < 8; ++i) {
        int r = i * 8 + ar;
        #pragma unroll
        for (int j = 0; j < 4; ++j) As[aidx(ac + j, r)] = ((const uint32*)&ra[i])[j];
        int n = i * 16 + br;
        *(uint4*)&Bs[bidx(n, bc)] = rb[i];
      }
      __syncthreads();
    }
  }
  // epilogue: stage C tile in LDS (reuse sm), stream out coalesced dwordx4
  float* Cs = (float*)sm;
  const int rl4 = (l >> 4) * 4;
  #pragma unroll
  for (int m = 0; m < 4; ++m) {
    int rbase = wm * 64 + m * 16 + rl4;
    #pragma unroll
    for (int n = 0; n < 4; ++n) {
      int cc = wn * 64 + n * 16 + fr;
      #pragma unroll
      for (int e = 0; e < 4; ++e) {
        int r = rbase + e;
        Cs[r * 128 + (cc ^ (((r >> 2) & 3) << 3))] = acc[m][n][e];
      }
    }
  }
  __syncthreads();
  float* cgp = C + (size_t)(bm * 128) * 1024 + bn * 128;
  #pragma unroll
  for (int it = 0; it < 16; ++it) {
    int idx = it * 256 + t;
    int r = idx >> 5, c4 = (idx & 31) * 4;
    float4 v = *(const float4*)&Cs[r * 128 + (c4 ^ (((r >> 2) & 3) << 3))];
    *(float4*)(cgp + (size_t)r * 1024 + c4) = v;
  }
}

// ---------------- tail: LN(xp+out) -> @W_out -> quat chain per row ----------------------------
DEV float wred64(float v) {
  #pragma unroll
  for (int m = 32; m; m >>= 1) v += __shfl_xor(v, m);
  return v;
}
DEV float4 qmul4(float4 a, float4 b) {
  return make_float4(
    a.x * b.x - a.y * b.y - a.z * b.z - a.w * b.w,
    a.x * b.y + a.y * b.x + a.z * b.w - a.w * b.z,
    a.x * b.z - a.y * b.w + a.z * b.x + a.w * b.y,
    a.x * b.w + a.y * b.z - a.z * b.y + a.w * b.x);
}
DEV float4 ln4q(float4 v, const float* g, const float* b) {
  float m = 0.25f * (v.x + v.y + v.z + v.w);
  float a0 = v.x - m, a1 = v.y - m, a2 = v.z - m, a3 = v.w - m;
  float var = 0.25f * (a0 * a0 + a1 * a1 + a2 * a2 + a3 * a3);
  float rs = 1.0f / sqrtf(var + 1e-5f);
  return make_float4(a0 * rs * g[0] + b[0], a1 * rs * g[1] + b[1],
                     a2 * rs * g[2] + b[2], a3 * rs * g[3] + b[3]);
}
DEV float4 qne(float4 q) {
  float n = sqrtf(q.x * q.x + q.y * q.y + q.z * q.z + q.w * q.w) + 1e-8f;
  float r = 1.0f / n;
  return make_float4(q.x * r, q.y * r, q.z * r, q.w * r);
}
DEV float gelu1(float v) { return 0.5f * v * (1.0f + erff(v * 0.70710678118654752440f)); }

__global__ __launch_bounds__(256) void kx_tail(const float* __restrict__ G,
    const float* __restrict__ x, const float* __restrict__ W_in, const float* __restrict__ b_in,
    const float* __restrict__ b_attn, const float* __restrict__ lng, const float* __restrict__ lnb,
    const float* __restrict__ W_out, const float* __restrict__ b_out,
    const float* __restrict__ thL, const float* __restrict__ thR,
    const float* __restrict__ Wf1, const float* __restrict__ bff1,
    const float* __restrict__ Wf2, const float* __restrict__ bff2,
    const float* __restrict__ n1g, const float* __restrict__ n1b,
    const float* __restrict__ n2g, const float* __restrict__ n2b,
    const float* __restrict__ n3g, const float* __restrict__ n3b,
    float* __restrict__ out, int rows0) {
  const int l = threadIdx.x & 63, w = threadIdx.x >> 6;
  const size_t rl = (size_t)blockIdx.x * 4 + w;
  const size_t rg = rows0 + rl;
  const float4 x4 = *(const float4*)(x + rg * 4);
  float4 tv[4];
  float lsum = 0.f;
  #pragma unroll
  for (int j = 0; j < 4; ++j) {
    int dd = j * 256 + l * 4;
    float4 g4 = *(const float4*)(G + rl * 1024 + dd);
    float4 w0 = *(const float4*)(W_in + dd);
    float4 w1 = *(const float4*)(W_in + 1024 + dd);
    float4 w2 = *(const float4*)(W_in + 2048 + dd);
    float4 w3 = *(const float4*)(W_in + 3072 + dd);
    float4 bi = *(const float4*)(b_in + dd);
    float4 ba = *(const float4*)(b_attn + dd);
    float4 o;
    o.x = g4.x + bi.x + ba.x + x4.x * w0.x + x4.y * w1.x + x4.z * w2.x + x4.w * w3.x;
    o.y = g4.y + bi.y + ba.y + x4.x * w0.y + x4.y * w1.y + x4.z * w2.y + x4.w * w3.y;
    o.z = g4.z + bi.z + ba.z + x4.x * w0.z + x4.y * w1.z + x4.z * w2.z + x4.w * w3.z;
    o.w = g4.w + bi.w + ba.w + x4.x * w0.w + x4.y * w1.w + x4.z * w2.w + x4.w * w3.w;
    tv[j] = o;
    lsum += o.x + o.y + o.z + o.w;
  }
  const float mean = wred64(lsum) * (1.0f / 1024.0f);
  float vsum = 0.f;
  #pragma unroll
  for (int j = 0; j < 4; ++j) {
    float a0 = tv[j].x - mean, a1 = tv[j].y - mean, a2 = tv[j].z - mean, a3 = tv[j].w - mean;
    vsum += a0 * a0 + a1 * a1 + a2 * a2 + a3 * a3;
  }
  const float rstd = 1.0f / sqrtf(wred64(vsum) * (1.0f / 1024.0f) + 1e-5f);
  float4 aq = make_float4(0.f, 0.f, 0.f, 0.f);
  #pragma unroll
  for (int j = 0; j < 4; ++j) {
    int dd = j * 256 + l * 4;
    float4 gg = *(const float4*)(lng + dd);
    float4 bb = *(const float4*)(lnb + dd);
    float av[4];
    av[0] = (tv[j].x - mean) * rstd * gg.x + bb.x;
    av[1] = (tv[j].y - mean) * rstd * gg.y + bb.y;
    av[2] = (tv[j].z - mean) * rstd * gg.z + bb.z;
    av[3] = (tv[j].w - mean) * rstd * gg.w + bb.w;
    #pragma unroll
    for (int e = 0; e < 4; ++e) {
      float4 wr = *(const float4*)(W_out + (size_t)(dd + e) * 4);
      aq.x = fmaf(av[e], wr.x, aq.x);
      aq.y = fmaf(av[e], wr.y, aq.y);
      aq.z = fmaf(av[e], wr.z, aq.z);
      aq.w = fmaf(av[e], wr.w, aq.w);
    }
  }
  aq.x = wred64(aq.x) + b_out[0];
  aq.y = wred64(aq.y) + b_out[1];
  aq.z = wred64(aq.z) + b_out[2];
  aq.w = wred64(aq.w) + b_out[3];
  float4 q1 = make_float4(x4.x + aq.x, x4.y + aq.y, x4.z + aq.z, x4.w + aq.w);
  float4 hq = qne(ln4q(q1, n1g, n1b));
  float4 o = hq;
  #pragma unroll
  for (int it = 0; it < 4; ++it) {
    float sl0, cl0, sl1, cl1, sl2, cl2;
    sincosf(0.5f * thL[it * 3 + 0], &sl0, &cl0);
    sincosf(0.5f * thL[it * 3 + 1], &sl1, &cl1);
    sincosf(0.5f * thL[it * 3 + 2], &sl2, &cl2);
    float4 qL = qne(make_float4(cl0 * cl1 * cl2, sl0 * cl1 * cl2, cl0 * sl1 * cl2, cl0 * cl1 * sl2));
    float sr0, cr0, sr1, cr1, sr2, cr2;
    sincosf(0.5f * thR[it * 3 + 0], &sr0, &cr0);
    sincosf(0.5f * thR[it * 3 + 1], &sr1, &cr1);
    sincosf(0.5f * thR[it * 3 + 2], &sr2, &cr2);
    float4 qR = qne(make_float4(cr0 * cr1 * cr2, sr0 * cr1 * cr2, cr0 * sr1 * cr2, cr0 * cr1 * sr2));
    float4 qRc = make_float4(qR.x, -qR.y, -qR.z, -qR.w);
    o = qmul4(qmul4(qL, o), qRc);
    o = qne(o);
  }
  float4 h2 = qne(ln4q(make_float4(hq.x + o.x, hq.y + o.y, hq.z + o.z, hq.w + o.w), n2g, n2b));
  float4 ffv = make_float4(bff2[0], bff2[1], bff2[2], bff2[3]);
  #pragma unroll
  for (int k = 0; k < 16; ++k) {
    float uv = bff1[k] + h2.x * Wf1[k] + h2.y * Wf1[16 + k] + h2.z * Wf1[32 + k] + h2.w * Wf1[48 + k];
    uv = gelu1(uv);
    ffv.x = fmaf(uv, Wf2[k * 4 + 0], ffv.x);
    ffv.y = fmaf(uv, Wf2[k * 4 + 1], ffv.y);
    ffv.z = fmaf(uv, Wf2[k * 4 + 2], ffv.z);
    ffv.w = fmaf(uv, Wf2[k * 4 + 3], ffv.w);
  }
  float4 h3 = qne(ln4q(make_float4(h2.x + ffv.x, h2.y + ffv.y, h2.z + ffv.z, h2.w + ffv.w), n3g, n3b));
  if (l == 0) *(float4*)(out + rg * 4) = h3;
}

extern "C" void kernel_launch(void* const* d_in, const int* in_sizes, int n_in,
                              void* d_out, int out_size, void* d_ws, size_t ws_size,
                              hipStream_t stream) {
  (void)in_sizes; (void)n_in; (void)out_size;
  const float* x      = (const float*)d_in[0];
  const float* W_in   = (const float*)d_in[1];
  const float* b_in   = (const float*)d_in[2];
  const float* abase  = (const float*)d_in[3];
  const float* pshift = (const float*)d_in[4];
  const float* Wattn  = (const float*)d_in[5];
  const float* battn  = (const float*)d_in[6];
  const float* lng    = (const float*)d_in[7];
  const float* lnb    = (const float*)d_in[8];
  const float* Wout   = (const float*)d_in[9];
  const float* bout   = (const float*)d_in[10];
  const float* thL    = (const float*)d_in[11];
  const float* thR    = (const float*)d_in[12];
  const float* Wf1    = (const float*)d_in[13];
  const float* bff1   = (const float*)d_in[14];
  const float* Wf2    = (const float*)d_in[15];
  const float* bff2   = (const float*)d_in[16];
  const float* n1g    = (const float*)d_in[17];
  const float* n1b    = (const float*)d_in[18];
  const float* n2g    = (const float*)d_in[19];
  const float* n2b    = (const float*)d_in[20];
  const float* n3g    = (const float*)d_in[21];
  const float* n3b    = (const float*)d_in[22];

  if (ws_size < (size_t)138459204) return;  // ~132 MiB
  char* ws = (char*)d_ws;
  float2* Zmid  = (float2*)ws;                       // 128MiB (fractal only)
  uint32* XFp   = (uint32*)ws;                       // 64MiB per half (packed filter out)
  float*  Cout  = (float*)(ws + 67108864);           // 64MiB per half (gemm out)
  uint32* W2    = (uint32*)(ws + 134217728);         // 4MiB packed W^T
  float* partials = (float*)(ws + 138412032);        // 32KB
  float* sparts   = (float*)(ws + 138444800);        // 6KB
  float* alphaw   = (float*)(ws + 138450944);        // 32B
  float* geluw    = (float*)(ws + 138451008);        // 8.2KB

  kx_fr_pass1<<<dim3(256, 8), 512, 0, stream>>>(x, W_in, b_in, Zmid);
  kx_fr_pass2<<<dim3(512, 8), 256, 0, stream>>>(Zmid, partials, sparts);
  kx_finalize<<<1, 512, 0, stream>>>(partials, sparts, alphaw, geluw);
  kx_wt<<<dim3(16, 16), 256, 0, stream>>>(Wattn, W2);
  for (int half = 0; half < 2; ++half) {
    kx_filter<<<dim3(16, 16, 4), 256, 0, stream>>>(x, W_in, b_in, alphaw, geluw,
                                                   abase, pshift, XFp, half * 4);
    kx_gemm<<<1024, 256, 0, stream>>>(XFp, W2, Cout);
    kx_tail<<<4096, 256, 0, stream>>>(Cout, x, W_in, b_in, battn, lng, lnb, Wout, bout,
                                      thL, thR, Wf1, bff1, Wf2, bff2,
                                      n1g, n1b, n2g, n2b, n3g, n3b,
                                      (float*)d_out, half * 16384);
  }
}

// Round 5
// 760.155 us; speedup vs baseline: 1.3390x; 1.2928x over previous
//
#include <hip/hip_runtime.h>
#include <hip/hip_bf16.h>
#include <math.h>

// PsiQRH block, MI355X. B=8 S=4096 QD=4 DM=1024 H=16 HD=64.
// Round 5: round-4 fp16 GEMM with compile fix (nontemporal store needs clang
// ext_vector_type, not HIP_vector_type float4).

#define DEV static __device__ __forceinline__
typedef unsigned int uint32;
typedef unsigned short u16;

typedef __attribute__((ext_vector_type(8))) _Float16 f16x8;
typedef __attribute__((ext_vector_type(4))) float f32x4;

DEV float2 cmulf(float2 a, float2 b) {
  return make_float2(a.x * b.x - a.y * b.y, a.x * b.y + a.y * b.x);
}
DEV u16 f2h(float f) {
  union { _Float16 h; u16 u; } v;
  v.h = (_Float16)f;
  return v.u;
}
DEV uint32 pack2h(float a, float b) {
  return (uint32)f2h(a) | ((uint32)f2h(b) << 16);
}
DEV void glds16(void* lds, const void* g) {
  __builtin_amdgcn_global_load_lds((const __attribute__((address_space(1))) unsigned int*)g,
                                   (__attribute__((address_space(3))) unsigned int*)lds, 16, 0, 0);
}

// ---------------- fractal pass 1: 1024-pt FFTs over a (z[n]=xp[2n]+i*xp[2n+1], n=2048a+b) ----
__global__ __launch_bounds__(512) void kx_fr_pass1(const float* __restrict__ x,
    const float* __restrict__ W_in, const float* __restrict__ b_in,
    float2* __restrict__ zmid) {
  __shared__ float2 fb[8 * 1024];
  const int t = threadIdx.x, l = t & 63, w = t >> 6;
  const int btile = blockIdx.x, bz = blockIdx.y;
  const int bcol = btile * 8 + w;
  const int d = 2 * (bcol & 511);
  const int soff = bcol >> 9;
  const float w00 = W_in[d],     w10 = W_in[1024 + d], w20 = W_in[2048 + d], w30 = W_in[3072 + d];
  const float w01 = W_in[d + 1], w11 = W_in[1025 + d], w21 = W_in[2049 + d], w31 = W_in[3073 + d];
  const float bi0 = b_in[d], bi1 = b_in[d + 1];
  const float* xb = x + (size_t)bz * 4096 * 4;
  #pragma unroll
  for (int i = 0; i < 16; ++i) {
    int a = i * 64 + l;
    int s = 4 * a + soff;
    float4 xv = *(const float4*)(xb + (size_t)s * 4);
    float z0 = fmaf(xv.x, w00, fmaf(xv.y, w10, fmaf(xv.z, w20, fmaf(xv.w, w30, bi0))));
    float z1 = fmaf(xv.x, w01, fmaf(xv.y, w11, fmaf(xv.z, w21, fmaf(xv.w, w31, bi1))));
    fb[w * 1024 + a] = make_float2(z0, z1);
  }
  __syncthreads();
  for (int st = 0; st < 10; ++st) {
    int hl = 9 - st;
    int half = 1 << hl;
    float invL = 1.0f / (float)(half << 1);
    #pragma unroll
    for (int u = 0; u < 8; ++u) {
      int bf = u * 64 + l;
      int blk = bf >> hl, tt = bf & (half - 1);
      int i1 = w * 1024 + (blk << (hl + 1)) + tt;
      float2 a0 = fb[i1], b0 = fb[i1 + half];
      float sn, cs;
      __sincosf(-6.28318530717958647692f * (float)tt * invL, &sn, &cs);
      fb[i1] = make_float2(a0.x + b0.x, a0.y + b0.y);
      fb[i1 + half] = cmulf(make_float2(a0.x - b0.x, a0.y - b0.y), make_float2(cs, sn));
    }
    __syncthreads();
  }
  float2* dst = zmid + (size_t)bz * (1024 * 2048);
  #pragma unroll
  for (int i = 0; i < 16; ++i) {
    int idx = i * 512 + t;
    int w8 = idx & 7, cnat = idx >> 3;
    float2 v = fb[w8 * 1024 + (int)(__brev((unsigned)cnat) >> 22)];
    dst[(size_t)cnat * 2048 + btile * 8 + w8] = v;
  }
}

DEV float block_reduce256(float* red, int t, float v) {
  red[t] = v; __syncthreads();
  for (int s = 128; s; s >>= 1) { if (t < s) red[t] += red[t + s]; __syncthreads(); }
  float r = red[0]; __syncthreads();
  return r;
}

// ---------------- fractal pass 2: twiddle + 2048-pt FFT over b, untwist, log-log moments -----
__global__ __launch_bounds__(256) void kx_fr_pass2(const float2* __restrict__ zmid,
    float* __restrict__ partials, float* __restrict__ sparts) {
  __shared__ float2 fb[2 * 2048];
  __shared__ float red[256];
  const int t = threadIdx.x, l = t & 63, w = t >> 6;
  const int cg = blockIdx.x, bz = blockIdx.y;
  const int col = w >> 1;
  const int l128 = (w & 1) * 64 + l;
  const int c = (cg == 0) ? (col ? 512 : 0) : (col ? (1024 - cg) : cg);
  const float2* src = zmid + ((size_t)bz * 1024 + c) * 2048;
  #pragma unroll
  for (int i = 0; i < 16; ++i) {
    int bb = i * 128 + l128;
    float2 z = src[bb];
    float fr = (float)(bb * c) * (1.0f / 2097152.0f);
    float sn, cs;
    __sincosf(-6.28318530717958647692f * fr, &sn, &cs);
    fb[col * 2048 + bb] = cmulf(z, make_float2(cs, sn));
  }
  __syncthreads();
  for (int st = 0; st < 11; ++st) {
    int hl = 10 - st;
    int half = 1 << hl;
    float invL = 1.0f / (float)(half << 1);
    #pragma unroll
    for (int u = 0; u < 8; ++u) {
      int bf = u * 128 + l128;
      int blk = bf >> hl, tt = bf & (half - 1);
      int i1 = col * 2048 + (blk << (hl + 1)) + tt;
      float2 a0 = fb[i1], b0 = fb[i1 + half];
      float sn, cs;
      __sincosf(-6.28318530717958647692f * (float)tt * invL, &sn, &cs);
      fb[i1] = make_float2(a0.x + b0.x, a0.y + b0.y);
      fb[i1 + half] = cmulf(make_float2(a0.x - b0.x, a0.y - b0.y), make_float2(cs, sn));
    }
    __syncthreads();
  }
  const int mcol = (cg == 0) ? col : (1 - col);
  float t0 = 0.f, t1 = 0.f, s0 = 0.f, s1 = 0.f, s2 = 0.f;
  #pragma unroll
  for (int i = 0; i < 16; ++i) {
    int dd = i * 128 + l128;
    int md = (c == 0) ? ((2048 - dd) & 2047) : (2047 - dd);
    float2 Zk = fb[col * 2048 + (int)(__brev((unsigned)dd) >> 21)];
    float2 Zm = fb[mcol * 2048 + (int)(__brev((unsigned)md) >> 21)];
    float2 E = make_float2(0.5f * (Zk.x + Zm.x), 0.5f * (Zk.y - Zm.y));
    float2 A = make_float2(Zk.x - Zm.x, Zk.y + Zm.y);
    float2 O = make_float2(0.5f * A.y, -0.5f * A.x);
    int k = c + (dd << 10);
    float fr = (float)k * (1.0f / 4194304.0f);
    float sn, cs;
    __sincosf(-6.28318530717958647692f * fr, &sn, &cs);
    float2 U = cmulf(make_float2(cs, sn), O);
    float Xr = E.x + U.x, Xi = E.y + U.y;
    float P = Xr * Xr + Xi * Xi;
    if (fr > 0.01f && fr < 0.5f) {
      float lp = logf(P + 1e-10f);
      float lk = logf(fr + 1e-10f);
      t0 += lp; t1 += lk * lp;
      s0 += 1.0f; s1 += lk; s2 += lk * lk;
    }
  }
  float T0 = block_reduce256(red, t, t0);
  float T1 = block_reduce256(red, t, t1);
  if (t == 0) {
    partials[((size_t)bz * 512 + cg) * 2 + 0] = T0;
    partials[((size_t)bz * 512 + cg) * 2 + 1] = T1;
  }
  if (bz == 0) {
    float S0 = block_reduce256(red, t, s0);
    float S1 = block_reduce256(red, t, s1);
    float S2 = block_reduce256(red, t, s2);
    if (t == 0) { sparts[cg * 3] = S0; sparts[cg * 3 + 1] = S1; sparts[cg * 3 + 2] = S2; }
  }
}

DEV float block_reduce512(float* sh, int t, float v) {
  sh[t] = v; __syncthreads();
  for (int s = 256; s; s >>= 1) { if (t < s) sh[t] += sh[t + s]; __syncthreads(); }
  float r = sh[0]; __syncthreads();
  return r;
}

// ---------------- finalize: alpha[b]; gelu_k table ---------------------------------------------
__global__ __launch_bounds__(512) void kx_finalize(const float* __restrict__ partials,
    const float* __restrict__ sparts, float* __restrict__ alpha, float* __restrict__ gelu) {
  __shared__ float sh[512];
  __shared__ float lk[4096];
  const int t = threadIdx.x;
  float S0 = block_reduce512(sh, t, sparts[t * 3 + 0]);
  float S1 = block_reduce512(sh, t, sparts[t * 3 + 1]);
  float S2 = block_reduce512(sh, t, sparts[t * 3 + 2]);
  float mk = S1 / S0;
  float var = S2 - mk * S1;
  for (int b = 0; b < 8; ++b) {
    float T0 = block_reduce512(sh, t, partials[((size_t)b * 512 + t) * 2 + 0]);
    float T1 = block_reduce512(sh, t, partials[((size_t)b * 512 + t) * 2 + 1]);
    if (t == 0) {
      float cov = T1 - mk * T0;
      float beta = -cov / (var + 1e-10f);
      float D = fminf(fmaxf((3.0f - beta) * 0.5f, 0.5f), 1.5f);
      alpha[b] = fminf(fmaxf(1.0f + 0.8f * (D - 1.0f), 0.1f), 3.0f);
    }
  }
  for (int s = t; s < 4096; s += 512) {
    int m = (s < 2048) ? s : (4096 - s);
    lk[s] = logf((float)m * (1.0f / 4096.0f) + 1e-8f);
  }
  __syncthreads();
  float ls = 0.f;
  for (int s = t; s < 4096; s += 512) ls += lk[s];
  float mean = block_reduce512(sh, t, ls) * (1.0f / 4096.0f);
  float vs = 0.f;
  for (int s = t; s < 4096; s += 512) { float dv = lk[s] - mean; vs += dv * dv; }
  float sd = sqrtf(block_reduce512(sh, t, vs) * (1.0f / 4095.0f));
  for (int k = t; k < 2049; k += 512) {
    float xn = (lk[k] - mean) / (sd + 1e-8f);
    gelu[k] = 0.5f * xn * (1.0f + erff(xn * 0.70710678118654752440f));
  }
}

// ---------------- W_attn_out transpose -> fp16 [n][d] pre-swizzled ----------------------------
// stored index within 64-d chunk: slot g8' = g8 ^ (n&7)  (16B granules)
__global__ __launch_bounds__(256) void kx_wt(const float* __restrict__ W, u16* __restrict__ Wt) {
  __shared__ float tile[64][65];
  const int t = threadIdx.x;
  const int nt = blockIdx.x, dt = blockIdx.y;
  #pragma unroll
  for (int i = 0; i < 16; ++i) {
    int idx = i * 256 + t;
    int r = idx >> 6, cc = idx & 63;
    tile[r][cc] = W[(size_t)(dt * 64 + r) * 1024 + nt * 64 + cc];
  }
  __syncthreads();
  #pragma unroll
  for (int i = 0; i < 2; ++i) {
    int task = i * 256 + t;
    int nl = task >> 3, g = task & 7;
    union { u16 h[8]; uint4 v; } pk;
    #pragma unroll
    for (int k = 0; k < 8; ++k) pk.h[k] = f2h(tile[g * 8 + k][nl]);
    size_t idx = (size_t)(nt * 64 + nl) * 1024 + dt * 64 + ((g ^ (nl & 7)) << 3);
    *(uint4*)(Wt + idx) = pk.v;
  }
}

// ---------------- spectral filter: irfft(rfft(xp)*cos(phase)) per (b,d), writes fp16 [bh][d][s]
__global__ __launch_bounds__(256) void kx_filter(const float* __restrict__ x,
    const float* __restrict__ W_in, const float* __restrict__ b_in,
    const float* __restrict__ alpha, const float* __restrict__ gelu,
    const float* __restrict__ alpha_base, const float* __restrict__ phase_shift,
    u16* __restrict__ xfh, int bz0) {
  __shared__ float2 fb[4 * 2048];
  const int t = threadIdx.x, l = t & 63, w = t >> 6;
  const int g = blockIdx.x, h = blockIdx.y, bhl = blockIdx.z;
  const int bz = bz0 + bhl;
  const int dphys = h * 64 + g * 4 + w;
  const float aa = alpha_base[h] * alpha[bz];
  const float ps = phase_shift[h];
  const float wq0 = W_in[dphys], wq1 = W_in[1024 + dphys], wq2 = W_in[2048 + dphys], wq3 = W_in[3072 + dphys];
  const float bi = b_in[dphys];
  const float* xb = x + (size_t)bz * 4096 * 4;
  const int base = w * 2048;
  #pragma unroll
  for (int i = 0; i < 32; ++i) {
    int m = i * 64 + l;
    float4 xa = *(const float4*)(xb + (size_t)(2 * m) * 4);
    float4 xc = *(const float4*)(xb + (size_t)(2 * m + 1) * 4);
    float z0 = fmaf(xa.x, wq0, fmaf(xa.y, wq1, fmaf(xa.z, wq2, fmaf(xa.w, wq3, bi))));
    float z1 = fmaf(xc.x, wq0, fmaf(xc.y, wq1, fmaf(xc.z, wq2, fmaf(xc.w, wq3, bi))));
    fb[base + m] = make_float2(z0, z1);
  }
  __syncthreads();
  for (int st = 0; st < 11; ++st) {
    int hl = 10 - st;
    int half = 1 << hl;
    float invL = 1.0f / (float)(half << 1);
    #pragma unroll
    for (int u = 0; u < 16; ++u) {
      int bf = u * 64 + l;
      int blk = bf >> hl, tt = bf & (half - 1);
      int i1 = base + (blk << (hl + 1)) + tt;
      float2 a0 = fb[i1], b0 = fb[i1 + half];
      float sn, cs;
      __sincosf(-6.28318530717958647692f * (float)tt * invL, &sn, &cs);
      fb[i1] = make_float2(a0.x + b0.x, a0.y + b0.y);
      fb[i1 + half] = cmulf(make_float2(a0.x - b0.x, a0.y - b0.y), make_float2(cs, sn));
    }
    __syncthreads();
  }
  #pragma unroll
  for (int i = 0; i < 17; ++i) {
    int k = i * 64 + l;
    if (k > 1024) continue;
    if (k == 0) {
      float2 Z0 = fb[base];
      float X0 = Z0.x + Z0.y;
      float XM = Z0.x - Z0.y;
      float g0 = cosf(fmaf(aa, gelu[0], ps));
      float gM = cosf(fmaf(aa, gelu[2048], ps));
      float Y0 = g0 * X0, YM = gM * XM;
      fb[base] = make_float2(0.5f * (Y0 + YM), 0.5f * (Y0 - YM));
    } else if (k == 1024) {
      float2 Z = fb[base + 1];
      float gk = cosf(fmaf(aa, gelu[1024], ps));
      fb[base + 1] = make_float2(gk * Z.x, gk * Z.y);
    } else {
      int p1 = (int)(__brev((unsigned)k) >> 21);
      int p2 = (int)(__brev((unsigned)(2048 - k)) >> 21);
      float2 Zk = fb[base + p1], Zm = fb[base + p2];
      float2 E = make_float2(0.5f * (Zk.x + Zm.x), 0.5f * (Zk.y - Zm.y));
      float2 A = make_float2(Zk.x - Zm.x, Zk.y + Zm.y);
      float2 O = make_float2(0.5f * A.y, -0.5f * A.x);
      float sn, cs;
      __sincosf(-3.14159265358979323846f * (float)k * (1.0f / 2048.0f), &sn, &cs);
      float2 U = cmulf(make_float2(cs, sn), O);
      float2 Xk = make_float2(E.x + U.x, E.y + U.y);
      float2 Xm = make_float2(E.x - U.x, -(E.y - U.y));
      float gk = cosf(fmaf(aa, gelu[k], ps));
      float gm = cosf(fmaf(aa, gelu[2048 - k], ps));
      float2 Yk = make_float2(gk * Xk.x, gk * Xk.y);
      float2 Ym = make_float2(gm * Xm.x, gm * Xm.y);
      float2 Ep = make_float2(0.5f * (Yk.x + Ym.x), 0.5f * (Yk.y - Ym.y));
      float2 Aq = make_float2(0.5f * (Yk.x - Ym.x), 0.5f * (Yk.y + Ym.y));
      float2 Op = cmulf(make_float2(cs, -sn), Aq);
      fb[base + p1] = make_float2(Ep.x - Op.y, Ep.y + Op.x);
      fb[base + p2] = make_float2(Ep.x + Op.y, -Ep.y + Op.x);
    }
  }
  __syncthreads();
  for (int st = 0; st < 11; ++st) {
    int half = 1 << st;
    float invL = 1.0f / (float)(half << 1);
    #pragma unroll
    for (int u = 0; u < 16; ++u) {
      int bf = u * 64 + l;
      int blk = bf >> st, tt = bf & (half - 1);
      int i1 = base + (blk << (st + 1)) + tt;
      float2 a0 = fb[i1], b0 = fb[i1 + half];
      float sn, cs;
      __sincosf(6.28318530717958647692f * (float)tt * invL, &sn, &cs);
      float2 tb = cmulf(b0, make_float2(cs, sn));
      fb[i1] = make_float2(a0.x + tb.x, a0.y + tb.y);
      fb[i1 + half] = make_float2(a0.x - tb.x, a0.y - tb.y);
    }
    __syncthreads();
  }
  uint32* rowu = (uint32*)(xfh + ((size_t)bhl * 1024 + dphys) * 4096);
  const float sc = 1.0f / 2048.0f;
  #pragma unroll
  for (int i = 0; i < 32; ++i) {
    int m = i * 64 + l;
    float2 v = fb[base + m];
    rowu[m] = pack2h(v.x * sc, v.y * sc);
  }
}

// ---------------- A transpose: fp16 [bh][d][s] -> fp16 [bh][s][d] pre-swizzled ----------------
// within each 64-d chunk: 16B slot g8' = g8 ^ (s&7)
__global__ __launch_bounds__(256) void kx_a16(const u16* __restrict__ XFh, u16* __restrict__ Aswz) {
  __shared__ uint32 tl[64][129];
  const int t = threadIdx.x;
  const int dt = blockIdx.x, st = blockIdx.y, bh = blockIdx.z;
  const u16* src = XFh + ((size_t)bh * 1024 + dt * 64) * 4096 + st * 256;
  #pragma unroll
  for (int i = 0; i < 8; ++i) {
    int dl = i * 8 + (t >> 5);
    int sl = (t & 31) * 8;
    uint4 v = *(const uint4*)(src + (size_t)dl * 4096 + sl);
    tl[dl][(t & 31) * 4 + 0] = v.x;
    tl[dl][(t & 31) * 4 + 1] = v.y;
    tl[dl][(t & 31) * 4 + 2] = v.z;
    tl[dl][(t & 31) * 4 + 3] = v.w;
  }
  __syncthreads();
  u16* dstb = Aswz + ((size_t)bh * 4096 + st * 256) * 1024 + dt * 64;
  #pragma unroll
  for (int j = 0; j < 8; ++j) {
    int task = j * 256 + t;
    int sl = task >> 3, g = task & 7;
    int sp = sl >> 1, sh = (sl & 1) * 16;
    uint4 ov;
    uint32 w0, w1;
    w0 = tl[g * 8 + 0][sp]; w1 = tl[g * 8 + 1][sp];
    ov.x = ((w0 >> sh) & 0xFFFFu) | (((w1 >> sh) & 0xFFFFu) << 16);
    w0 = tl[g * 8 + 2][sp]; w1 = tl[g * 8 + 3][sp];
    ov.y = ((w0 >> sh) & 0xFFFFu) | (((w1 >> sh) & 0xFFFFu) << 16);
    w0 = tl[g * 8 + 4][sp]; w1 = tl[g * 8 + 5][sp];
    ov.z = ((w0 >> sh) & 0xFFFFu) | (((w1 >> sh) & 0xFFFFu) << 16);
    w0 = tl[g * 8 + 6][sp]; w1 = tl[g * 8 + 7][sp];
    ov.w = ((w0 >> sh) & 0xFFFFu) | (((w1 >> sh) & 0xFFFFu) << 16);
    *(uint4*)(dstb + (size_t)sl * 1024 + ((g ^ (sl & 7)) << 3)) = ov;
  }
}

// ---------------- fp16 MFMA GEMM: C[16384x1024] = A*W, A pre-swizzled [s][d] ------------------
__global__ __launch_bounds__(256) void kx_gemm(const u16* __restrict__ A,
    const u16* __restrict__ Bw, float* __restrict__ C) {
  __shared__ u16 sm[32768];              // 64KB: As[2]*16KB + Bs[2]*16KB; epilogue Cs f32[128][128]
  const int t = threadIdx.x, l = t & 63, w = t >> 6;
  const int wm = w >> 1, wn = w & 1;
  const int id = blockIdx.x;
  const int wg = (id & 7) * 128 + (id >> 3);        // XCD-contiguous bm chunks
  const int bm = wg >> 3, bn = wg & 7;
  const int bh = bm >> 5;
  const u16* Ab = A + ((size_t)(bh * 4096 + (bm & 31) * 128)) * 1024;
  const u16* Bb = Bw + (size_t)(bn * 128) * 1024;
  const int fr = l & 15;
  const int lr = l >> 3, lg = l & 7;                // staging: row-in-chunk, 16B slot
  f32x4 acc[4][4];
  #pragma unroll
  for (int m = 0; m < 4; ++m)
    #pragma unroll
    for (int n = 0; n < 4; ++n) acc[m][n] = (f32x4){0.f, 0.f, 0.f, 0.f};

  // stage kt into buf: 16 chunks x 1KB each side; wave w does chunks j*4+w
  #define STAGE(KT, BUF) { \
    u16* Ad = sm + (BUF) * 8192; \
    u16* Bd = sm + 16384 + (BUF) * 8192; \
    _Pragma("unroll") \
    for (int j = 0; j < 4; ++j) { \
      int q = j * 4 + w; \
      glds16((void*)(Ad + q * 512), Ab + (size_t)(q * 8 + lr) * 1024 + (KT) * 64 + lg * 8); \
      glds16((void*)(Bd + q * 512), Bb + (size_t)(q * 8 + lr) * 1024 + (KT) * 64 + lg * 8); \
    } }

  STAGE(0, 0);
  __syncthreads();
  for (int kt = 0; kt < 16; ++kt) {
    const int cur = kt & 1;
    if (kt < 15) STAGE(kt + 1, cur ^ 1);
    const u16* Ac = sm + cur * 8192;
    const u16* Bc = sm + 16384 + cur * 8192;
    #pragma unroll
    for (int kk = 0; kk < 2; ++kk) {
      const int g8r = kk * 4 + (l >> 4);
      f16x8 af[4], bf[4];
      #pragma unroll
      for (int m = 0; m < 4; ++m) {
        int s = wm * 64 + m * 16 + fr;
        af[m] = *(const f16x8*)&Ac[s * 64 + ((g8r ^ (s & 7)) << 3)];
      }
      #pragma unroll
      for (int n = 0; n < 4; ++n) {
        int nn = wn * 64 + n * 16 + fr;
        bf[n] = *(const f16x8*)&Bc[nn * 64 + ((g8r ^ (nn & 7)) << 3)];
      }
      #pragma unroll
      for (int m = 0; m < 4; ++m)
        #pragma unroll
        for (int n = 0; n < 4; ++n)
          acc[m][n] = __builtin_amdgcn_mfma_f32_16x16x32_f16(af[m], bf[n], acc[m][n], 0, 0, 0);
    }
    __syncthreads();
  }
  // epilogue: stage C tile in LDS (reuse sm), stream out coalesced nontemporal dwordx4
  float* Cs = (float*)sm;
  const int rl4 = (l >> 4) * 4;
  #pragma unroll
  for (int m = 0; m < 4; ++m) {
    int rbase = wm * 64 + m * 16 + rl4;
    #pragma unroll
    for (int n = 0; n < 4; ++n) {
      int cc = wn * 64 + n * 16 + fr;
      #pragma unroll
      for (int e = 0; e < 4; ++e) {
        int r = rbase + e;
        Cs[r * 128 + (cc ^ (((r >> 2) & 3) << 3))] = acc[m][n][e];
      }
    }
  }
  __syncthreads();
  float* cgp = C + (size_t)(bm * 128) * 1024 + bn * 128;
  #pragma unroll
  for (int it = 0; it < 16; ++it) {
    int idx = it * 256 + t;
    int r = idx >> 5, c4 = (idx & 31) * 4;
    f32x4 v = *(const f32x4*)&Cs[r * 128 + (c4 ^ (((r >> 2) & 3) << 3))];
    __builtin_nontemporal_store(v, (f32x4*)(cgp + (size_t)r * 1024 + c4));
  }
}

// ---------------- tail: LN(xp+out) -> @W_out -> quat chain per row ----------------------------
DEV float wred64(float v) {
  #pragma unroll
  for (int m = 32; m; m >>= 1) v += __shfl_xor(v, m);
  return v;
}
DEV float4 qmul4(float4 a, float4 b) {
  return make_float4(
    a.x * b.x - a.y * b.y - a.z * b.z - a.w * b.w,
    a.x * b.y + a.y * b.x + a.z * b.w - a.w * b.z,
    a.x * b.z - a.y * b.w + a.z * b.x + a.w * b.y,
    a.x * b.w + a.y * b.z - a.z * b.y + a.w * b.x);
}
DEV float4 ln4q(float4 v, const float* g, const float* b) {
  float m = 0.25f * (v.x + v.y + v.z + v.w);
  float a0 = v.x - m, a1 = v.y - m, a2 = v.z - m, a3 = v.w - m;
  float var = 0.25f * (a0 * a0 + a1 * a1 + a2 * a2 + a3 * a3);
  float rs = 1.0f / sqrtf(var + 1e-5f);
  return make_float4(a0 * rs * g[0] + b[0], a1 * rs * g[1] + b[1],
                     a2 * rs * g[2] + b[2], a3 * rs * g[3] + b[3]);
}
DEV float4 qne(float4 q) {
  float n = sqrtf(q.x * q.x + q.y * q.y + q.z * q.z + q.w * q.w) + 1e-8f;
  float r = 1.0f / n;
  return make_float4(q.x * r, q.y * r, q.z * r, q.w * r);
}
DEV float gelu1(float v) { return 0.5f * v * (1.0f + erff(v * 0.70710678118654752440f)); }

__global__ __launch_bounds__(256) void kx_tail(const float* __restrict__ G,
    const float* __restrict__ x, const float* __restrict__ W_in, const float* __restrict__ b_in,
    const float* __restrict__ b_attn, const float* __restrict__ lng, const float* __restrict__ lnb,
    const float* __restrict__ W_out, const float* __restrict__ b_out,
    const float* __restrict__ thL, const float* __restrict__ thR,
    const float* __restrict__ Wf1, const float* __restrict__ bff1,
    const float* __restrict__ Wf2, const float* __restrict__ bff2,
    const float* __restrict__ n1g, const float* __restrict__ n1b,
    const float* __restrict__ n2g, const float* __restrict__ n2b,
    const float* __restrict__ n3g, const float* __restrict__ n3b,
    float* __restrict__ out, int rows0) {
  const int l = threadIdx.x & 63, w = threadIdx.x >> 6;
  const size_t rl = (size_t)blockIdx.x * 4 + w;
  const size_t rg = rows0 + rl;
  const float4 x4 = *(const float4*)(x + rg * 4);
  float4 tv[4];
  float lsum = 0.f;
  #pragma unroll
  for (int j = 0; j < 4; ++j) {
    int dd = j * 256 + l * 4;
    float4 g4 = *(const float4*)(G + rl * 1024 + dd);
    float4 w0 = *(const float4*)(W_in + dd);
    float4 w1 = *(const float4*)(W_in + 1024 + dd);
    float4 w2 = *(const float4*)(W_in + 2048 + dd);
    float4 w3 = *(const float4*)(W_in + 3072 + dd);
    float4 bi = *(const float4*)(b_in + dd);
    float4 ba = *(const float4*)(b_attn + dd);
    float4 o;
    o.x = g4.x + bi.x + ba.x + x4.x * w0.x + x4.y * w1.x + x4.z * w2.x + x4.w * w3.x;
    o.y = g4.y + bi.y + ba.y + x4.x * w0.y + x4.y * w1.y + x4.z * w2.y + x4.w * w3.y;
    o.z = g4.z + bi.z + ba.z + x4.x * w0.z + x4.y * w1.z + x4.z * w2.z + x4.w * w3.z;
    o.w = g4.w + bi.w + ba.w + x4.x * w0.w + x4.y * w1.w + x4.z * w2.w + x4.w * w3.w;
    tv[j] = o;
    lsum += o.x + o.y + o.z + o.w;
  }
  const float mean = wred64(lsum) * (1.0f / 1024.0f);
  float vsum = 0.f;
  #pragma unroll
  for (int j = 0; j < 4; ++j) {
    float a0 = tv[j].x - mean, a1 = tv[j].y - mean, a2 = tv[j].z - mean, a3 = tv[j].w - mean;
    vsum += a0 * a0 + a1 * a1 + a2 * a2 + a3 * a3;
  }
  const float rstd = 1.0f / sqrtf(wred64(vsum) * (1.0f / 1024.0f) + 1e-5f);
  float4 aq = make_float4(0.f, 0.f, 0.f, 0.f);
  #pragma unroll
  for (int j = 0; j < 4; ++j) {
    int dd = j * 256 + l * 4;
    float4 gg = *(const float4*)(lng + dd);
    float4 bb = *(const float4*)(lnb + dd);
    float av[4];
    av[0] = (tv[j].x - mean) * rstd * gg.x + bb.x;
    av[1] = (tv[j].y - mean) * rstd * gg.y + bb.y;
    av[2] = (tv[j].z - mean) * rstd * gg.z + bb.z;
    av[3] = (tv[j].w - mean) * rstd * gg.w + bb.w;
    #pragma unroll
    for (int e = 0; e < 4; ++e) {
      float4 wr = *(const float4*)(W_out + (size_t)(dd + e) * 4);
      aq.x = fmaf(av[e], wr.x, aq.x);
      aq.y = fmaf(av[e], wr.y, aq.y);
      aq.z = fmaf(av[e], wr.z, aq.z);
      aq.w = fmaf(av[e], wr.w, aq.w);
    }
  }
  aq.x = wred64(aq.x) + b_out[0];
  aq.y = wred64(aq.y) + b_out[1];
  aq.z = wred64(aq.z) + b_out[2];
  aq.w = wred64(aq.w) + b_out[3];
  float4 q1 = make_float4(x4.x + aq.x, x4.y + aq.y, x4.z + aq.z, x4.w + aq.w);
  float4 hq = qne(ln4q(q1, n1g, n1b));
  float4 o = hq;
  #pragma unroll
  for (int it = 0; it < 4; ++it) {
    float sl0, cl0, sl1, cl1, sl2, cl2;
    sincosf(0.5f * thL[it * 3 + 0], &sl0, &cl0);
    sincosf(0.5f * thL[it * 3 + 1], &sl1, &cl1);
    sincosf(0.5f * thL[it * 3 + 2], &sl2, &cl2);
    float4 qL = qne(make_float4(cl0 * cl1 * cl2, sl0 * cl1 * cl2, cl0 * sl1 * cl2, cl0 * cl1 * sl2));
    float sr0, cr0, sr1, cr1, sr2, cr2;
    sincosf(0.5f * thR[it * 3 + 0], &sr0, &cr0);
    sincosf(0.5f * thR[it * 3 + 1], &sr1, &cr1);
    sincosf(0.5f * thR[it * 3 + 2], &sr2, &cr2);
    float4 qR = qne(make_float4(cr0 * cr1 * cr2, sr0 * cr1 * cr2, cr0 * sr1 * cr2, cr0 * cr1 * sr2));
    float4 qRc = make_float4(qR.x, -qR.y, -qR.z, -qR.w);
    o = qmul4(qmul4(qL, o), qRc);
    o = qne(o);
  }
  float4 h2 = qne(ln4q(make_float4(hq.x + o.x, hq.y + o.y, hq.z + o.z, hq.w + o.w), n2g, n2b));
  float4 ffv = make_float4(bff2[0], bff2[1], bff2[2], bff2[3]);
  #pragma unroll
  for (int k = 0; k < 16; ++k) {
    float uv = bff1[k] + h2.x * Wf1[k] + h2.y * Wf1[16 + k] + h2.z * Wf1[32 + k] + h2.w * Wf1[48 + k];
    uv = gelu1(uv);
    ffv.x = fmaf(uv, Wf2[k * 4 + 0], ffv.x);
    ffv.y = fmaf(uv, Wf2[k * 4 + 1], ffv.y);
    ffv.z = fmaf(uv, Wf2[k * 4 + 2], ffv.z);
    ffv.w = fmaf(uv, Wf2[k * 4 + 3], ffv.w);
  }
  float4 h3 = qne(ln4q(make_float4(h2.x + ffv.x, h2.y + ffv.y, h2.z + ffv.z, h2.w + ffv.w), n3g, n3b));
  if (l == 0) *(float4*)(out + rg * 4) = h3;
}

extern "C" void kernel_launch(void* const* d_in, const int* in_sizes, int n_in,
                              void* d_out, int out_size, void* d_ws, size_t ws_size,
                              hipStream_t stream) {
  (void)in_sizes; (void)n_in; (void)out_size;
  const float* x      = (const float*)d_in[0];
  const float* W_in   = (const float*)d_in[1];
  const float* b_in   = (const float*)d_in[2];
  const float* abase  = (const float*)d_in[3];
  const float* pshift = (const float*)d_in[4];
  const float* Wattn  = (const float*)d_in[5];
  const float* battn  = (const float*)d_in[6];
  const float* lng    = (const float*)d_in[7];
  const float* lnb    = (const float*)d_in[8];
  const float* Wout   = (const float*)d_in[9];
  const float* bout   = (const float*)d_in[10];
  const float* thL    = (const float*)d_in[11];
  const float* thR    = (const float*)d_in[12];
  const float* Wf1    = (const float*)d_in[13];
  const float* bff1   = (const float*)d_in[14];
  const float* Wf2    = (const float*)d_in[15];
  const float* bff2   = (const float*)d_in[16];
  const float* n1g    = (const float*)d_in[17];
  const float* n1b    = (const float*)d_in[18];
  const float* n2g    = (const float*)d_in[19];
  const float* n2b    = (const float*)d_in[20];
  const float* n3g    = (const float*)d_in[21];
  const float* n3b    = (const float*)d_in[22];

  if (ws_size < (size_t)138459204) return;  // ~132 MiB
  char* ws = (char*)d_ws;
  float2* Zmid  = (float2*)ws;                       // 128MiB (fractal only)
  u16*   XFh    = (u16*)ws;                          // 32MiB per half (filter out, fp16 [bh][d][s])
  u16*   Aswz   = (u16*)(ws + 33554432);             // 32MiB per half (A fp16 [bh][s][d] pre-swizzled)
  float* Cout   = (float*)(ws + 67108864);           // 64MiB per half (gemm out)
  u16*   W2h    = (u16*)(ws + 134217728);            // 2MiB fp16 W^T pre-swizzled
  float* partials = (float*)(ws + 138412032);        // 32KB
  float* sparts   = (float*)(ws + 138444800);        // 6KB
  float* alphaw   = (float*)(ws + 138450944);        // 32B
  float* geluw    = (float*)(ws + 138451008);        // 8.2KB

  kx_fr_pass1<<<dim3(256, 8), 512, 0, stream>>>(x, W_in, b_in, Zmid);
  kx_fr_pass2<<<dim3(512, 8), 256, 0, stream>>>(Zmid, partials, sparts);
  kx_finalize<<<1, 512, 0, stream>>>(partials, sparts, alphaw, geluw);
  kx_wt<<<dim3(16, 16), 256, 0, stream>>>(Wattn, W2h);
  for (int half = 0; half < 2; ++half) {
    kx_filter<<<dim3(16, 16, 4), 256, 0, stream>>>(x, W_in, b_in, alphaw, geluw,
                                                   abase, pshift, XFh, half * 4);
    kx_a16<<<dim3(16, 16, 4), 256, 0, stream>>>(XFh, Aswz);
    kx_gemm<<<1024, 256, 0, stream>>>(Aswz, W2h, Cout);
    kx_tail<<<4096, 256, 0, stream>>>(Cout, x, W_in, b_in, battn, lng, lnb, Wout, bout,
                                      thL, thR, Wf1, bff1, Wf2, bff2,
                                      n1g, n1b, n2g, n2b, n3g, n3b,
                                      (float*)d_out, half * 16384);
  }
}

// Round 6
// 631.217 us; speedup vs baseline: 1.6126x; 1.2043x over previous
//
#include <hip/hip_runtime.h>
#include <hip/hip_bf16.h>
#include <math.h>

// PsiQRH block, MI355X. B=8 S=4096 QD=4 DM=1024 H=16 HD=64.
// Round 6: FFT twiddles via 1-sincos/stage + compile-time 16th-root constants;
// pass2 untwist coalesced (kills 32-way LDS conflict); filter as complex-pair
// 4096-FFT with precomputed gain table (no untwist, half the stages per channel).

#define DEV static __device__ __forceinline__
typedef unsigned int uint32;
typedef unsigned short u16;

typedef __attribute__((ext_vector_type(8))) _Float16 f16x8;
typedef __attribute__((ext_vector_type(4))) float f32x4;

DEV float2 cmulf(float2 a, float2 b) {
  return make_float2(a.x * b.x - a.y * b.y, a.x * b.y + a.y * b.x);
}
DEV u16 f2h(float f) {
  union { _Float16 h; u16 u; } v;
  v.h = (_Float16)f;
  return v.u;
}
DEV void glds16(void* lds, const void* g) {
  __builtin_amdgcn_global_load_lds((const __attribute__((address_space(1))) unsigned int*)g,
                                   (__attribute__((address_space(3))) unsigned int*)lds, 16, 0, 0);
}

// cos/sin of pi*j/16, j = 0..15 (compile-time twiddle correction factors)
constexpr float CR_C[16] = {
  1.0f, 0.980785280403230f, 0.923879532511287f, 0.831469612302545f,
  0.707106781186548f, 0.555570233019602f, 0.382683432365090f, 0.195090322016128f,
  0.0f, -0.195090322016128f, -0.382683432365090f, -0.555570233019602f,
  -0.707106781186548f, -0.831469612302545f, -0.923879532511287f, -0.980785280403230f };
constexpr float CR_S[16] = {
  0.0f, 0.195090322016128f, 0.382683432365090f, 0.555570233019602f,
  0.707106781186548f, 0.831469612302545f, 0.923879532511287f, 0.980785280403230f,
  1.0f, 0.980785280403230f, 0.923879532511287f, 0.831469612302545f,
  0.707106781186548f, 0.555570233019602f, 0.382683432365090f, 0.195090322016128f };
constexpr int REV4[16] = {0,8,4,12,2,10,6,14,1,9,5,13,3,11,7,15};

// DIF radix-2, natural in -> bitrev out. Group of L lanes handles one N=2^NLOG FFT.
// Twiddle e^{-i pi tt/half} = e^{-i pi (lg mod half)/half} * e^{-i pi ((u*L) mod half)/half},
// second factor is a compile-time 16th root (16*L >= N guaranteed by our uses).
template<int L, int NLOG>
DEV void dif_stages(float2* fbg, int lg) {
  #pragma unroll
  for (int st = 0; st < NLOG; ++st) {
    const int hl = NLOG - 1 - st;
    const int half = 1 << hl;
    float bs, bc;
    __sincosf((float)(lg & (half - 1)) * (-3.14159265358979323846f / (float)half), &bs, &bc);
    const float2 base = make_float2(bc, bs);
    #pragma unroll
    for (int u = 0; u < (1 << (NLOG - 1)) / L; ++u) {
      const int m = (u * L) & (half - 1);
      const int j = m * 16 / half;
      const float2 tf = (m == 0) ? base
                                 : cmulf(base, make_float2(CR_C[j], -CR_S[j]));
      const int bf = u * L + lg;
      const int i1 = ((bf >> hl) << (hl + 1)) + (bf & (half - 1));
      const float2 a0 = fbg[i1], b0 = fbg[i1 + half];
      fbg[i1] = make_float2(a0.x + b0.x, a0.y + b0.y);
      fbg[i1 + half] = cmulf(make_float2(a0.x - b0.x, a0.y - b0.y), tf);
    }
    __syncthreads();
  }
}

// DIT radix-2, bitrev in -> natural out (positive exponent).
template<int L, int NLOG>
DEV void dit_stages(float2* fbg, int lg) {
  #pragma unroll
  for (int st = 0; st < NLOG; ++st) {
    const int half = 1 << st;
    float bs, bc;
    __sincosf((float)(lg & (half - 1)) * (3.14159265358979323846f / (float)half), &bs, &bc);
    const float2 base = make_float2(bc, bs);
    #pragma unroll
    for (int u = 0; u < (1 << (NLOG - 1)) / L; ++u) {
      const int m = (u * L) & (half - 1);
      const int j = m * 16 / half;
      const float2 tf = (m == 0) ? base
                                 : cmulf(base, make_float2(CR_C[j], CR_S[j]));
      const int bf = u * L + lg;
      const int i1 = ((bf >> st) << (st + 1)) + (bf & (half - 1));
      const float2 a0 = fbg[i1], b0 = fbg[i1 + half];
      const float2 tb = cmulf(b0, tf);
      fbg[i1] = make_float2(a0.x + tb.x, a0.y + tb.y);
      fbg[i1 + half] = make_float2(a0.x - tb.x, a0.y - tb.y);
    }
    __syncthreads();
  }
}

// ---------------- fractal pass 1: 1024-pt FFTs over a (z[n]=xp[2n]+i*xp[2n+1], n=2048a+b) ----
__global__ __launch_bounds__(512) void kx_fr_pass1(const float* __restrict__ x,
    const float* __restrict__ W_in, const float* __restrict__ b_in,
    float2* __restrict__ zmid) {
  __shared__ float2 fb[8 * 1024];
  const int t = threadIdx.x, l = t & 63, w = t >> 6;
  const int btile = blockIdx.x, bz = blockIdx.y;
  const int bcol = btile * 8 + w;
  const int d = 2 * (bcol & 511);
  const int soff = bcol >> 9;
  const float w00 = W_in[d],     w10 = W_in[1024 + d], w20 = W_in[2048 + d], w30 = W_in[3072 + d];
  const float w01 = W_in[d + 1], w11 = W_in[1025 + d], w21 = W_in[2049 + d], w31 = W_in[3073 + d];
  const float bi0 = b_in[d], bi1 = b_in[d + 1];
  const float* xb = x + (size_t)bz * 4096 * 4;
  #pragma unroll
  for (int i = 0; i < 16; ++i) {
    int a = i * 64 + l;
    int s = 4 * a + soff;
    float4 xv = *(const float4*)(xb + (size_t)s * 4);
    float z0 = fmaf(xv.x, w00, fmaf(xv.y, w10, fmaf(xv.z, w20, fmaf(xv.w, w30, bi0))));
    float z1 = fmaf(xv.x, w01, fmaf(xv.y, w11, fmaf(xv.z, w21, fmaf(xv.w, w31, bi1))));
    fb[w * 1024 + a] = make_float2(z0, z1);
  }
  __syncthreads();
  dif_stages<64, 10>(fb + w * 1024, l);
  float2* dst = zmid + (size_t)bz * (1024 * 2048);
  #pragma unroll
  for (int i = 0; i < 16; ++i) {
    int idx = i * 512 + t;
    int w8 = idx & 7, cnat = idx >> 3;
    float2 v = fb[w8 * 1024 + (int)(__brev((unsigned)cnat) >> 22)];
    dst[(size_t)cnat * 2048 + btile * 8 + w8] = v;
  }
}

DEV float block_reduce256(float* red, int t, float v) {
  red[t] = v; __syncthreads();
  for (int s = 128; s; s >>= 1) { if (t < s) red[t] += red[t + s]; __syncthreads(); }
  float r = red[0]; __syncthreads();
  return r;
}

// ---------------- fractal pass 2: twiddle + 2048-pt FFT over b, untwist, log-log moments -----
__global__ __launch_bounds__(256) void kx_fr_pass2(const float2* __restrict__ zmid,
    float* __restrict__ partials, float* __restrict__ sparts) {
  __shared__ float2 fb[2 * 2048];
  __shared__ float red[256];
  const int t = threadIdx.x, l = t & 63, w = t >> 6;
  const int cg = blockIdx.x, bz = blockIdx.y;
  const int col = w >> 1;
  const int l128 = (w & 1) * 64 + l;
  const int c = (cg == 0) ? (col ? 512 : 0) : (col ? (1024 - cg) : cg);
  const float2* src = zmid + ((size_t)bz * 1024 + c) * 2048;
  // four-step inter-twiddle via rotation recurrence: e^{-2pi i bb*c/2^21}
  float2 rot, stp;
  {
    float sn, cs;
    __sincosf((float)(l128 * c) * (-6.28318530717958647692f / 2097152.0f), &sn, &cs);
    rot = make_float2(cs, sn);
    __sincosf((float)c * (-6.28318530717958647692f / 16384.0f), &sn, &cs);
    stp = make_float2(cs, sn);
  }
  #pragma unroll
  for (int i = 0; i < 16; ++i) {
    int bb = i * 128 + l128;
    fb[col * 2048 + bb] = cmulf(src[bb], rot);
    rot = cmulf(rot, stp);
  }
  __syncthreads();
  dif_stages<128, 11>(fb + col * 2048, l128);
  // untwist + log-log moments
  float t0 = 0.f, t1 = 0.f, s0 = 0.f, s1 = 0.f, s2 = 0.f;
  if (cg != 0) {
    // coalesced: iterate bitrev positions p; dd=rev11(p); mirror md=2047-dd at pos 2047-p
    const int mcol = 1 - col;
    float2 pw[16];
    pw[0] = make_float2(1.f, 0.f);
    {
      float sn, cs;
      __sincosf(-3.14159265358979323846f / 2048.0f, &sn, &cs);
      float2 w1 = make_float2(cs, sn);
      #pragma unroll
      for (int j = 1; j < 16; ++j) pw[j] = cmulf(pw[j - 1], w1);
    }
    const int rl = (int)(__brev((unsigned)l128) >> 25);   // rev7(l128)
    float2 base2;
    {
      float sn, cs;
      __sincosf((float)rl * (-3.14159265358979323846f / 128.0f), &sn, &cs);
      float2 lf = make_float2(cs, sn);
      __sincosf((float)c * (-6.28318530717958647692f / 4194304.0f), &sn, &cs);
      base2 = cmulf(make_float2(cs, sn), lf);
    }
    #pragma unroll
    for (int i = 0; i < 16; ++i) {
      const int p = i * 128 + l128;
      const int dd = (rl << 4) | REV4[i];
      float2 Zk = fb[col * 2048 + p];
      float2 Zm = fb[mcol * 2048 + (2047 - p)];
      float2 E = make_float2(0.5f * (Zk.x + Zm.x), 0.5f * (Zk.y - Zm.y));
      float2 A = make_float2(Zk.x - Zm.x, Zk.y + Zm.y);
      float2 O = make_float2(0.5f * A.y, -0.5f * A.x);
      float2 urot = cmulf(base2, pw[REV4[i]]);
      float2 U = cmulf(urot, O);
      float Xr = E.x + U.x, Xi = E.y + U.y;
      float P = Xr * Xr + Xi * Xi;
      int k = c + (dd << 10);
      float fr = (float)k * (1.0f / 4194304.0f);
      if (fr > 0.01f && fr < 0.5f) {
        float lp = logf(P + 1e-10f);
        float lk = logf(fr + 1e-10f);
        t0 += lp; t1 += lk * lp;
        s0 += 1.0f; s1 += lk; s2 += lk * lk;
      }
    }
  } else {
    // c in {0,512}: self-mirrored columns, scattered reads (1 block per bz, negligible)
    const int mcol = col;
    float2 urot;
    {
      float sn, cs;
      __sincosf((float)(c + l128 * 1024) * (-6.28318530717958647692f / 4194304.0f), &sn, &cs);
      urot = make_float2(cs, sn);
    }
    const float2 ustp = make_float2(0.980785280403230f, -0.195090322016128f); // e^{-i pi/16}
    #pragma unroll
    for (int i = 0; i < 16; ++i) {
      int dd = i * 128 + l128;
      int md = (c == 0) ? ((2048 - dd) & 2047) : (2047 - dd);
      float2 Zk = fb[col * 2048 + (int)(__brev((unsigned)dd) >> 21)];
      float2 Zm = fb[mcol * 2048 + (int)(__brev((unsigned)md) >> 21)];
      float2 E = make_float2(0.5f * (Zk.x + Zm.x), 0.5f * (Zk.y - Zm.y));
      float2 A = make_float2(Zk.x - Zm.x, Zk.y + Zm.y);
      float2 O = make_float2(0.5f * A.y, -0.5f * A.x);
      float2 U = cmulf(urot, O);
      float Xr = E.x + U.x, Xi = E.y + U.y;
      float P = Xr * Xr + Xi * Xi;
      int k = c + (dd << 10);
      float fr = (float)k * (1.0f / 4194304.0f);
      if (fr > 0.01f && fr < 0.5f) {
        float lp = logf(P + 1e-10f);
        float lk = logf(fr + 1e-10f);
        t0 += lp; t1 += lk * lp;
        s0 += 1.0f; s1 += lk; s2 += lk * lk;
      }
      urot = cmulf(urot, ustp);
    }
  }
  float T0 = block_reduce256(red, t, t0);
  float T1 = block_reduce256(red, t, t1);
  if (t == 0) {
    partials[((size_t)bz * 512 + cg) * 2 + 0] = T0;
    partials[((size_t)bz * 512 + cg) * 2 + 1] = T1;
  }
  if (bz == 0) {
    float S0 = block_reduce256(red, t, s0);
    float S1 = block_reduce256(red, t, s1);
    float S2 = block_reduce256(red, t, s2);
    if (t == 0) { sparts[cg * 3] = S0; sparts[cg * 3 + 1] = S1; sparts[cg * 3 + 2] = S2; }
  }
}

DEV float block_reduce512(float* sh, int t, float v) {
  sh[t] = v; __syncthreads();
  for (int s = 256; s; s >>= 1) { if (t < s) sh[t] += sh[t + s]; __syncthreads(); }
  float r = sh[0]; __syncthreads();
  return r;
}

// ---------------- finalize: alpha[b]; gelu_k table ---------------------------------------------
__global__ __launch_bounds__(512) void kx_finalize(const float* __restrict__ partials,
    const float* __restrict__ sparts, float* __restrict__ alpha, float* __restrict__ gelu) {
  __shared__ float sh[512];
  __shared__ float lk[4096];
  const int t = threadIdx.x;
  float S0 = block_reduce512(sh, t, sparts[t * 3 + 0]);
  float S1 = block_reduce512(sh, t, sparts[t * 3 + 1]);
  float S2 = block_reduce512(sh, t, sparts[t * 3 + 2]);
  float mk = S1 / S0;
  float var = S2 - mk * S1;
  for (int b = 0; b < 8; ++b) {
    float T0 = block_reduce512(sh, t, partials[((size_t)b * 512 + t) * 2 + 0]);
    float T1 = block_reduce512(sh, t, partials[((size_t)b * 512 + t) * 2 + 1]);
    if (t == 0) {
      float cov = T1 - mk * T0;
      float beta = -cov / (var + 1e-10f);
      float D = fminf(fmaxf((3.0f - beta) * 0.5f, 0.5f), 1.5f);
      alpha[b] = fminf(fmaxf(1.0f + 0.8f * (D - 1.0f), 0.1f), 3.0f);
    }
  }
  for (int s = t; s < 4096; s += 512) {
    int m = (s < 2048) ? s : (4096 - s);
    lk[s] = logf((float)m * (1.0f / 4096.0f) + 1e-8f);
  }
  __syncthreads();
  float ls = 0.f;
  for (int s = t; s < 4096; s += 512) ls += lk[s];
  float mean = block_reduce512(sh, t, ls) * (1.0f / 4096.0f);
  float vs = 0.f;
  for (int s = t; s < 4096; s += 512) { float dv = lk[s] - mean; vs += dv * dv; }
  float sd = sqrtf(block_reduce512(sh, t, vs) * (1.0f / 4095.0f));
  for (int k = t; k < 2049; k += 512) {
    float xn = (lk[k] - mean) / (sd + 1e-8f);
    gelu[k] = 0.5f * xn * (1.0f + erff(xn * 0.70710678118654752440f));
  }
}

// ---------------- gain table: gains[b*16+h][k] = cos(alpha_base[h]*alpha[b]*gelu[k] + ps[h]) --
__global__ __launch_bounds__(256) void kx_gains(const float* __restrict__ alpha,
    const float* __restrict__ gelu, const float* __restrict__ abase,
    const float* __restrict__ pshift, float* __restrict__ gains) {
  const int bh = blockIdx.x;    // 0..127
  const float aa = abase[bh & 15] * alpha[bh >> 4];
  const float ps = pshift[bh & 15];
  for (int k = threadIdx.x; k < 2049; k += 256)
    gains[(size_t)bh * 2064 + k] = cosf(fmaf(aa, gelu[k], ps));
}

// ---------------- W_attn_out transpose -> fp16 [n][d] pre-swizzled ----------------------------
__global__ __launch_bounds__(256) void kx_wt(const float* __restrict__ W, u16* __restrict__ Wt) {
  __shared__ float tile[64][65];
  const int t = threadIdx.x;
  const int nt = blockIdx.x, dt = blockIdx.y;
  #pragma unroll
  for (int i = 0; i < 16; ++i) {
    int idx = i * 256 + t;
    int r = idx >> 6, cc = idx & 63;
    tile[r][cc] = W[(size_t)(dt * 64 + r) * 1024 + nt * 64 + cc];
  }
  __syncthreads();
  #pragma unroll
  for (int i = 0; i < 2; ++i) {
    int task = i * 256 + t;
    int nl = task >> 3, g = task & 7;
    union { u16 h[8]; uint4 v; } pk;
    #pragma unroll
    for (int k = 0; k < 8; ++k) pk.h[k] = f2h(tile[g * 8 + k][nl]);
    size_t idx = (size_t)(nt * 64 + nl) * 1024 + dt * 64 + ((g ^ (nl & 7)) << 3);
    *(uint4*)(Wt + idx) = pk.v;
  }
}

// ---------------- spectral filter: complex-pair 4096-FFT, real symmetric gain -----------------
// group q (128 lanes) packs channels (d0, d0+1) as re/im of one 4096-pt complex FFT.
__global__ __launch_bounds__(256) void kx_filter(const float* __restrict__ x,
    const float* __restrict__ W_in, const float* __restrict__ b_in,
    const float* __restrict__ gains, u16* __restrict__ xfh, int bz0) {
  __shared__ float2 fb[2 * 4096];
  const int t = threadIdx.x;
  const int lg = t & 127, q = t >> 7;
  const int g = blockIdx.x, h = blockIdx.y, bhl = blockIdx.z;
  const int bz = bz0 + bhl;
  const int d0 = h * 64 + g * 4 + q * 2;
  const float* gn = gains + ((size_t)bz * 16 + h) * 2064;
  const float wa0 = W_in[d0],     wa1 = W_in[1024 + d0], wa2 = W_in[2048 + d0], wa3 = W_in[3072 + d0];
  const float wb0 = W_in[d0 + 1], wb1 = W_in[1025 + d0], wb2 = W_in[2049 + d0], wb3 = W_in[3073 + d0];
  const float bia = b_in[d0], bib = b_in[d0 + 1];
  const float* xb = x + (size_t)bz * 4096 * 4;
  float2* fbg = fb + q * 4096;
  #pragma unroll
  for (int i = 0; i < 32; ++i) {
    int s = i * 128 + lg;
    float4 xv = *(const float4*)(xb + (size_t)s * 4);
    float za = fmaf(xv.x, wa0, fmaf(xv.y, wa1, fmaf(xv.z, wa2, fmaf(xv.w, wa3, bia))));
    float zb = fmaf(xv.x, wb0, fmaf(xv.y, wb1, fmaf(xv.z, wb2, fmaf(xv.w, wb3, bib))));
    fbg[s] = make_float2(za, zb);
  }
  __syncthreads();
  dif_stages<128, 12>(fbg, lg);
  // pointwise gain (data bitrev): k = rev12(p), gain = gn[min(k, 4096-k)]
  #pragma unroll
  for (int i = 0; i < 32; ++i) {
    int p = i * 128 + lg;
    int k = (int)(__brev((unsigned)p) >> 20);
    int km = (k < 2048) ? k : (4096 - k);
    float gk = gn[km];
    float2 v = fbg[p];
    fbg[p] = make_float2(v.x * gk, v.y * gk);
  }
  __syncthreads();
  dit_stages<128, 12>(fbg, lg);
  u16* rowa = xfh + ((size_t)bhl * 1024 + d0) * 4096;
  u16* rowb = rowa + 4096;
  const float sc = 1.0f / 4096.0f;
  #pragma unroll
  for (int i = 0; i < 32; ++i) {
    int s = i * 128 + lg;
    float2 v = fbg[s];
    rowa[s] = f2h(v.x * sc);
    rowb[s] = f2h(v.y * sc);
  }
}

// ---------------- A transpose: fp16 [bh][d][s] -> fp16 [bh][s][d] pre-swizzled ----------------
__global__ __launch_bounds__(256) void kx_a16(const u16* __restrict__ XFh, u16* __restrict__ Aswz) {
  __shared__ uint32 tl[64][129];
  const int t = threadIdx.x;
  const int dt = blockIdx.x, st = blockIdx.y, bh = blockIdx.z;
  const u16* src = XFh + ((size_t)bh * 1024 + dt * 64) * 4096 + st * 256;
  #pragma unroll
  for (int i = 0; i < 8; ++i) {
    int dl = i * 8 + (t >> 5);
    int sl = (t & 31) * 8;
    uint4 v = *(const uint4*)(src + (size_t)dl * 4096 + sl);
    tl[dl][(t & 31) * 4 + 0] = v.x;
    tl[dl][(t & 31) * 4 + 1] = v.y;
    tl[dl][(t & 31) * 4 + 2] = v.z;
    tl[dl][(t & 31) * 4 + 3] = v.w;
  }
  __syncthreads();
  u16* dstb = Aswz + ((size_t)bh * 4096 + st * 256) * 1024 + dt * 64;
  #pragma unroll
  for (int j = 0; j < 8; ++j) {
    int task = j * 256 + t;
    int sl = task >> 3, g = task & 7;
    int sp = sl >> 1, sh = (sl & 1) * 16;
    uint4 ov;
    uint32 w0, w1;
    w0 = tl[g * 8 + 0][sp]; w1 = tl[g * 8 + 1][sp];
    ov.x = ((w0 >> sh) & 0xFFFFu) | (((w1 >> sh) & 0xFFFFu) << 16);
    w0 = tl[g * 8 + 2][sp]; w1 = tl[g * 8 + 3][sp];
    ov.y = ((w0 >> sh) & 0xFFFFu) | (((w1 >> sh) & 0xFFFFu) << 16);
    w0 = tl[g * 8 + 4][sp]; w1 = tl[g * 8 + 5][sp];
    ov.z = ((w0 >> sh) & 0xFFFFu) | (((w1 >> sh) & 0xFFFFu) << 16);
    w0 = tl[g * 8 + 6][sp]; w1 = tl[g * 8 + 7][sp];
    ov.w = ((w0 >> sh) & 0xFFFFu) | (((w1 >> sh) & 0xFFFFu) << 16);
    *(uint4*)(dstb + (size_t)sl * 1024 + ((g ^ (sl & 7)) << 3)) = ov;
  }
}

// ---------------- fp16 MFMA GEMM: C[16384x1024] = A*W, A pre-swizzled [s][d] ------------------
__global__ __launch_bounds__(256) void kx_gemm(const u16* __restrict__ A,
    const u16* __restrict__ Bw, float* __restrict__ C) {
  __shared__ u16 sm[32768];
  const int t = threadIdx.x, l = t & 63, w = t >> 6;
  const int wm = w >> 1, wn = w & 1;
  const int id = blockIdx.x;
  const int wg = (id & 7) * 128 + (id >> 3);
  const int bm = wg >> 3, bn = wg & 7;
  const int bh = bm >> 5;
  const u16* Ab = A + ((size_t)(bh * 4096 + (bm & 31) * 128)) * 1024;
  const u16* Bb = Bw + (size_t)(bn * 128) * 1024;
  const int fr = l & 15;
  const int lr = l >> 3, lg = l & 7;
  f32x4 acc[4][4];
  #pragma unroll
  for (int m = 0; m < 4; ++m)
    #pragma unroll
    for (int n = 0; n < 4; ++n) acc[m][n] = (f32x4){0.f, 0.f, 0.f, 0.f};

  #define STAGE(KT, BUF) { \
    u16* Ad = sm + (BUF) * 8192; \
    u16* Bd = sm + 16384 + (BUF) * 8192; \
    _Pragma("unroll") \
    for (int j = 0; j < 4; ++j) { \
      int qq = j * 4 + w; \
      glds16((void*)(Ad + qq * 512), Ab + (size_t)(qq * 8 + lr) * 1024 + (KT) * 64 + lg * 8); \
      glds16((void*)(Bd + qq * 512), Bb + (size_t)(qq * 8 + lr) * 1024 + (KT) * 64 + lg * 8); \
    } }

  STAGE(0, 0);
  __syncthreads();
  for (int kt = 0; kt < 16; ++kt) {
    const int cur = kt & 1;
    if (kt < 15) STAGE(kt + 1, cur ^ 1);
    const u16* Ac = sm + cur * 8192;
    const u16* Bc = sm + 16384 + cur * 8192;
    #pragma unroll
    for (int kk = 0; kk < 2; ++kk) {
      const int g8r = kk * 4 + (l >> 4);
      f16x8 af[4], bf[4];
      #pragma unroll
      for (int m = 0; m < 4; ++m) {
        int s = wm * 64 + m * 16 + fr;
        af[m] = *(const f16x8*)&Ac[s * 64 + ((g8r ^ (s & 7)) << 3)];
      }
      #pragma unroll
      for (int n = 0; n < 4; ++n) {
        int nn = wn * 64 + n * 16 + fr;
        bf[n] = *(const f16x8*)&Bc[nn * 64 + ((g8r ^ (nn & 7)) << 3)];
      }
      #pragma unroll
      for (int m = 0; m < 4; ++m)
        #pragma unroll
        for (int n = 0; n < 4; ++n)
          acc[m][n] = __builtin_amdgcn_mfma_f32_16x16x32_f16(af[m], bf[n], acc[m][n], 0, 0, 0);
    }
    __syncthreads();
  }
  float* Cs = (float*)sm;
  const int rl4 = (l >> 4) * 4;
  #pragma unroll
  for (int m = 0; m < 4; ++m) {
    int rbase = wm * 64 + m * 16 + rl4;
    #pragma unroll
    for (int n = 0; n < 4; ++n) {
      int cc = wn * 64 + n * 16 + fr;
      #pragma unroll
      for (int e = 0; e < 4; ++e) {
        int r = rbase + e;
        Cs[r * 128 + (cc ^ (((r >> 2) & 3) << 3))] = acc[m][n][e];
      }
    }
  }
  __syncthreads();
  float* cgp = C + (size_t)(bm * 128) * 1024 + bn * 128;
  #pragma unroll
  for (int it = 0; it < 16; ++it) {
    int idx = it * 256 + t;
    int r = idx >> 5, c4 = (idx & 31) * 4;
    f32x4 v = *(const f32x4*)&Cs[r * 128 + (c4 ^ (((r >> 2) & 3) << 3))];
    __builtin_nontemporal_store(v, (f32x4*)(cgp + (size_t)r * 1024 + c4));
  }
}

// ---------------- tail: LN(xp+out) -> @W_out -> quat chain per row ----------------------------
DEV float wred64(float v) {
  #pragma unroll
  for (int m = 32; m; m >>= 1) v += __shfl_xor(v, m);
  return v;
}
DEV float4 qmul4(float4 a, float4 b) {
  return make_float4(
    a.x * b.x - a.y * b.y - a.z * b.z - a.w * b.w,
    a.x * b.y + a.y * b.x + a.z * b.w - a.w * b.z,
    a.x * b.z - a.y * b.w + a.z * b.x + a.w * b.y,
    a.x * b.w + a.y * b.z - a.z * b.y + a.w * b.x);
}
DEV float4 ln4q(float4 v, const float* g, const float* b) {
  float m = 0.25f * (v.x + v.y + v.z + v.w);
  float a0 = v.x - m, a1 = v.y - m, a2 = v.z - m, a3 = v.w - m;
  float var = 0.25f * (a0 * a0 + a1 * a1 + a2 * a2 + a3 * a3);
  float rs = 1.0f / sqrtf(var + 1e-5f);
  return make_float4(a0 * rs * g[0] + b[0], a1 * rs * g[1] + b[1],
                     a2 * rs * g[2] + b[2], a3 * rs * g[3] + b[3]);
}
DEV float4 qne(float4 q) {
  float n = sqrtf(q.x * q.x + q.y * q.y + q.z * q.z + q.w * q.w) + 1e-8f;
  float r = 1.0f / n;
  return make_float4(q.x * r, q.y * r, q.z * r, q.w * r);
}
DEV float gelu1(float v) { return 0.5f * v * (1.0f + erff(v * 0.70710678118654752440f)); }

__global__ __launch_bounds__(256) void kx_tail(const float* __restrict__ G,
    const float* __restrict__ x, const float* __restrict__ W_in, const float* __restrict__ b_in,
    const float* __restrict__ b_attn, const float* __restrict__ lng, const float* __restrict__ lnb,
    const float* __restrict__ W_out, const float* __restrict__ b_out,
    const float* __restrict__ thL, const float* __restrict__ thR,
    const float* __restrict__ Wf1, const float* __restrict__ bff1,
    const float* __restrict__ Wf2, const float* __restrict__ bff2,
    const float* __restrict__ n1g, const float* __restrict__ n1b,
    const float* __restrict__ n2g, const float* __restrict__ n2b,
    const float* __restrict__ n3g, const float* __restrict__ n3b,
    float* __restrict__ out, int rows0) {
  const int l = threadIdx.x & 63, w = threadIdx.x >> 6;
  const size_t rl = (size_t)blockIdx.x * 4 + w;
  const size_t rg = rows0 + rl;
  const float4 x4 = *(const float4*)(x + rg * 4);
  float4 tv[4];
  float lsum = 0.f;
  #pragma unroll
  for (int j = 0; j < 4; ++j) {
    int dd = j * 256 + l * 4;
    float4 g4 = *(const float4*)(G + rl * 1024 + dd);
    float4 w0 = *(const float4*)(W_in + dd);
    float4 w1 = *(const float4*)(W_in + 1024 + dd);
    float4 w2 = *(const float4*)(W_in + 2048 + dd);
    float4 w3 = *(const float4*)(W_in + 3072 + dd);
    float4 bi = *(const float4*)(b_in + dd);
    float4 ba = *(const float4*)(b_attn + dd);
    float4 o;
    o.x = g4.x + bi.x + ba.x + x4.x * w0.x + x4.y * w1.x + x4.z * w2.x + x4.w * w3.x;
    o.y = g4.y + bi.y + ba.y + x4.x * w0.y + x4.y * w1.y + x4.z * w2.y + x4.w * w3.y;
    o.z = g4.z + bi.z + ba.z + x4.x * w0.z + x4.y * w1.z + x4.z * w2.z + x4.w * w3.z;
    o.w = g4.w + bi.w + ba.w + x4.x * w0.w + x4.y * w1.w + x4.z * w2.w + x4.w * w3.w;
    tv[j] = o;
    lsum += o.x + o.y + o.z + o.w;
  }
  const float mean = wred64(lsum) * (1.0f / 1024.0f);
  float vsum = 0.f;
  #pragma unroll
  for (int j = 0; j < 4; ++j) {
    float a0 = tv[j].x - mean, a1 = tv[j].y - mean, a2 = tv[j].z - mean, a3 = tv[j].w - mean;
    vsum += a0 * a0 + a1 * a1 + a2 * a2 + a3 * a3;
  }
  const float rstd = 1.0f / sqrtf(wred64(vsum) * (1.0f / 1024.0f) + 1e-5f);
  float4 aq = make_float4(0.f, 0.f, 0.f, 0.f);
  #pragma unroll
  for (int j = 0; j < 4; ++j) {
    int dd = j * 256 + l * 4;
    float4 gg = *(const float4*)(lng + dd);
    float4 bb = *(const float4*)(lnb + dd);
    float av[4];
    av[0] = (tv[j].x - mean) * rstd * gg.x + bb.x;
    av[1] = (tv[j].y - mean) * rstd * gg.y + bb.y;
    av[2] = (tv[j].z - mean) * rstd * gg.z + bb.z;
    av[3] = (tv[j].w - mean) * rstd * gg.w + bb.w;
    #pragma unroll
    for (int e = 0; e < 4; ++e) {
      float4 wr = *(const float4*)(W_out + (size_t)(dd + e) * 4);
      aq.x = fmaf(av[e], wr.x, aq.x);
      aq.y = fmaf(av[e], wr.y, aq.y);
      aq.z = fmaf(av[e], wr.z, aq.z);
      aq.w = fmaf(av[e], wr.w, aq.w);
    }
  }
  aq.x = wred64(aq.x) + b_out[0];
  aq.y = wred64(aq.y) + b_out[1];
  aq.z = wred64(aq.z) + b_out[2];
  aq.w = wred64(aq.w) + b_out[3];
  float4 q1 = make_float4(x4.x + aq.x, x4.y + aq.y, x4.z + aq.z, x4.w + aq.w);
  float4 hq = qne(ln4q(q1, n1g, n1b));
  float4 o = hq;
  #pragma unroll
  for (int it = 0; it < 4; ++it) {
    float sl0, cl0, sl1, cl1, sl2, cl2;
    sincosf(0.5f * thL[it * 3 + 0], &sl0, &cl0);
    sincosf(0.5f * thL[it * 3 + 1], &sl1, &cl1);
    sincosf(0.5f * thL[it * 3 + 2], &sl2, &cl2);
    float4 qL = qne(make_float4(cl0 * cl1 * cl2, sl0 * cl1 * cl2, cl0 * sl1 * cl2, cl0 * cl1 * sl2));
    float sr0, cr0, sr1, cr1, sr2, cr2;
    sincosf(0.5f * thR[it * 3 + 0], &sr0, &cr0);
    sincosf(0.5f * thR[it * 3 + 1], &sr1, &cr1);
    sincosf(0.5f * thR[it * 3 + 2], &sr2, &cr2);
    float4 qR = qne(make_float4(cr0 * cr1 * cr2, sr0 * cr1 * cr2, cr0 * sr1 * cr2, cr0 * cr1 * sr2));
    float4 qRc = make_float4(qR.x, -qR.y, -qR.z, -qR.w);
    o = qmul4(qmul4(qL, o), qRc);
    o = qne(o);
  }
  float4 h2 = qne(ln4q(make_float4(hq.x + o.x, hq.y + o.y, hq.z + o.z, hq.w + o.w), n2g, n2b));
  float4 ffv = make_float4(bff2[0], bff2[1], bff2[2], bff2[3]);
  #pragma unroll
  for (int k = 0; k < 16; ++k) {
    float uv = bff1[k] + h2.x * Wf1[k] + h2.y * Wf1[16 + k] + h2.z * Wf1[32 + k] + h2.w * Wf1[48 + k];
    uv = gelu1(uv);
    ffv.x = fmaf(uv, Wf2[k * 4 + 0], ffv.x);
    ffv.y = fmaf(uv, Wf2[k * 4 + 1], ffv.y);
    ffv.z = fmaf(uv, Wf2[k * 4 + 2], ffv.z);
    ffv.w = fmaf(uv, Wf2[k * 4 + 3], ffv.w);
  }
  float4 h3 = qne(ln4q(make_float4(h2.x + ffv.x, h2.y + ffv.y, h2.z + ffv.z, h2.w + ffv.w), n3g, n3b));
  if (l == 0) *(float4*)(out + rg * 4) = h3;
}

extern "C" void kernel_launch(void* const* d_in, const int* in_sizes, int n_in,
                              void* d_out, int out_size, void* d_ws, size_t ws_size,
                              hipStream_t stream) {
  (void)in_sizes; (void)n_in; (void)out_size;
  const float* x      = (const float*)d_in[0];
  const float* W_in   = (const float*)d_in[1];
  const float* b_in   = (const float*)d_in[2];
  const float* abase  = (const float*)d_in[3];
  const float* pshift = (const float*)d_in[4];
  const float* Wattn  = (const float*)d_in[5];
  const float* battn  = (const float*)d_in[6];
  const float* lng    = (const float*)d_in[7];
  const float* lnb    = (const float*)d_in[8];
  const float* Wout   = (const float*)d_in[9];
  const float* bout   = (const float*)d_in[10];
  const float* thL    = (const float*)d_in[11];
  const float* thR    = (const float*)d_in[12];
  const float* Wf1    = (const float*)d_in[13];
  const float* bff1   = (const float*)d_in[14];
  const float* Wf2    = (const float*)d_in[15];
  const float* bff2   = (const float*)d_in[16];
  const float* n1g    = (const float*)d_in[17];
  const float* n1b    = (const float*)d_in[18];
  const float* n2g    = (const float*)d_in[19];
  const float* n2b    = (const float*)d_in[20];
  const float* n3g    = (const float*)d_in[21];
  const float* n3b    = (const float*)d_in[22];

  if (ws_size < (size_t)138459204) return;  // ~132 MiB
  char* ws = (char*)d_ws;
  float2* Zmid  = (float2*)ws;                       // 128MiB (fractal only)
  u16*   XFh    = (u16*)ws;                          // 32MiB per half (filter out, fp16 [bh][d][s])
  u16*   Aswz   = (u16*)(ws + 33554432);             // 32MiB per half (A fp16 [bh][s][d] pre-swizzled)
  float* Cout   = (float*)(ws + 67108864);           // 64MiB per half (gemm out)
  u16*   W2h    = (u16*)(ws + 134217728);            // 2MiB fp16 W^T pre-swizzled
  float* gainsw = (float*)(ws + 136314880);          // ~1MiB gain table [128][2064]
  float* partials = (float*)(ws + 138412032);        // 32KB
  float* sparts   = (float*)(ws + 138444800);        // 6KB
  float* alphaw   = (float*)(ws + 138450944);        // 32B
  float* geluw    = (float*)(ws + 138451008);        // 8.2KB

  kx_fr_pass1<<<dim3(256, 8), 512, 0, stream>>>(x, W_in, b_in, Zmid);
  kx_fr_pass2<<<dim3(512, 8), 256, 0, stream>>>(Zmid, partials, sparts);
  kx_finalize<<<1, 512, 0, stream>>>(partials, sparts, alphaw, geluw);
  kx_gains<<<128, 256, 0, stream>>>(alphaw, geluw, abase, pshift, gainsw);
  kx_wt<<<dim3(16, 16), 256, 0, stream>>>(Wattn, W2h);
  for (int half = 0; half < 2; ++half) {
    kx_filter<<<dim3(16, 16, 4), 256, 0, stream>>>(x, W_in, b_in, gainsw, XFh, half * 4);
    kx_a16<<<dim3(16, 16, 4), 256, 0, stream>>>(XFh, Aswz);
    kx_gemm<<<1024, 256, 0, stream>>>(Aswz, W2h, Cout);
    kx_tail<<<4096, 256, 0, stream>>>(Cout, x, W_in, b_in, battn, lng, lnb, Wout, bout,
                                      thL, thR, Wf1, bff1, Wf2, bff2,
                                      n1g, n1b, n2g, n2b, n3g, n3b,
                                      (float*)d_out, half * 16384);
  }
}